// Round 2
// baseline (1044.327 us; speedup 1.0000x reference)
//
#include <hip/hip_runtime.h>
#include <hip/hip_bf16.h>

// Problem constants
#define N_ATOM 2000
#define MNBR   12
#define OFEA   92
#define AF     64
#define BFEA   41
#define K1     169   // 2A+B
#define O1     128
#define OE     82
#define NM     24000
#define NCONV  3
#define HID    128
#define NCRY   64
#define EPS_BN 1e-5f

#define LDA_T  192   // bf16 weight leading dim (169 padded to 192)
#define LDSW   88    // LDS row pitch (ushorts) for MFMA tiles
#define LDE    48    // padded E stride (41 -> 48, float4-aligned rows)
#define LDP    260   // HPQ row pitch (floats): 256 + 4 pad (2-way-free banks)
#define TPB    512
#define NBLK   250   // 24000 rows / 96 rows-per-block (exact)

typedef __bf16 bf16x8 __attribute__((ext_vector_type(8)));
typedef float  f32x4  __attribute__((ext_vector_type(4)));

// -------- dynamic LDS layout (bytes) --------
#define AS_OFF    0            // ushort As[96][88]   = 16,896
#define WS_OFF    16896        // ushort Ws[512][88]  = 90,112   } union
#define HPQ_OFF   16896        // float HPQ[96][260]  = 99,840   } union
#define BL_OFF    116736       // float bL[512]       = 2,048
#define SCT_OFF   118784       // float scT[256]
#define SHT_OFF   119808       // float shT[256]
#define SC3_OFF   120832       // float sc3[128]
#define SH3_OFF   121344       // float sh3[128]
#define S13_OFF   121856       // float s13L[128]
#define S23_OFF   122368       // float s23L[128]
#define TBL_OFF   122880       // float tbL[512]      = 2,048
#define DYN_LDS   124928

__device__ __forceinline__ float sigmoidf_(float x){
    return __builtin_amdgcn_rcpf(1.f + __expf(-x));
}
__device__ __forceinline__ float softplusf_(float x){
    return fmaxf(x,0.f) + __logf(1.f + __expf(-fabsf(x)));
}
__device__ __forceinline__ uint4 pack_bf16_8(const float* v){
    __hip_bfloat16 o[8];
    #pragma unroll
    for (int j=0;j<8;j++) o[j] = __float2bfloat16(v[j]);
    return *(const uint4*)o;
}
__device__ __forceinline__ float aloadf(const float* p){
    return __hip_atomic_load((float*)p, __ATOMIC_RELAXED, __HIP_MEMORY_SCOPE_AGENT);
}

// software grid barrier: bar[0]=cnt, bar[1]=gen (both zeroed before launch)
__device__ __forceinline__ void gridbar(unsigned* bar, unsigned target){
    __syncthreads();
    if (threadIdx.x == 0){
        unsigned* cnt = bar;
        unsigned* gen = bar + 1;
        unsigned g = __hip_atomic_load(gen, __ATOMIC_RELAXED, __HIP_MEMORY_SCOPE_AGENT);
        unsigned a = __hip_atomic_fetch_add(cnt, 1u, __ATOMIC_ACQ_REL, __HIP_MEMORY_SCOPE_AGENT);
        if (a + 1 == target){
            __hip_atomic_store(cnt, 0u, __ATOMIC_RELAXED, __HIP_MEMORY_SCOPE_AGENT);
            __hip_atomic_fetch_add(gen, 1u, __ATOMIC_RELEASE, __HIP_MEMORY_SCOPE_AGENT);
        } else {
            while (__hip_atomic_load(gen, __ATOMIC_ACQUIRE, __HIP_MEMORY_SCOPE_AGENT) == g)
                __builtin_amdgcn_s_sleep(4);
        }
    }
    __syncthreads();
}

// ============================================================================
// MEGA: per conv layer, one kernel. Block = 8 atoms (96 rows) x all 512 cols.
// GEMM -> block-local BN stats -> gridbar -> BN finalize -> consumer math
// -> TB stats -> gridbar -> x-update.  No REST/TB round-trips.
// STL: S1A[0..255] S2A[256..511] S13[512..639] S23[640..767] S12[768..831] S22[832..895]
// ============================================================================
__global__ __launch_bounds__(TPB, 2)
void mega_k(float* __restrict__ X, float* __restrict__ E48,
            const int* __restrict__ idx,
            const __hip_bfloat16* __restrict__ W, const float* __restrict__ bias,
            float* __restrict__ STL, unsigned* __restrict__ bar,
            const float* __restrict__ g1, const float* __restrict__ b1,
            const float* __restrict__ ge, const float* __restrict__ be,
            const float* __restrict__ g3, const float* __restrict__ b3b,
            const float* __restrict__ g2, const float* __restrict__ b2)
{
    extern __shared__ char smem[];
    unsigned short (*As)[LDSW] = (unsigned short(*)[LDSW])(smem + AS_OFF);
    unsigned short (*Ws)[LDSW] = (unsigned short(*)[LDSW])(smem + WS_OFF);
    float (*HPQ)[LDP] = (float(*)[LDP])(smem + HPQ_OFF);
    float* bL   = (float*)(smem + BL_OFF);
    float* scT  = (float*)(smem + SCT_OFF);
    float* shT  = (float*)(smem + SHT_OFF);
    float* sc3  = (float*)(smem + SC3_OFF);
    float* sh3  = (float*)(smem + SH3_OFF);
    float* s13L = (float*)(smem + S13_OFF);
    float* s23L = (float*)(smem + S23_OFF);
    float* tbL  = (float*)(smem + TBL_OFF);

    const int tid = threadIdx.x;
    const int w    = tid >> 6;
    const int l    = tid & 63;
    const int wm   = w >> 2;      // 0..1 row half
    const int cg   = w & 3;       // 0..3 col group (128 cols each)
    const int lrow = l & 15;
    const int quad = l >> 4;
    const int row0 = blockIdx.x * 96;
    const int atomBase = blockIdx.x * 8;

    bL[tid] = bias[tid];
    if (tid < 128){ s13L[tid] = 0.f; s23L[tid] = 0.f; }

    f32x4 acc[3][8];
    #pragma unroll
    for (int i=0;i<3;i++)
        #pragma unroll
        for (int j=0;j<8;j++) acc[i][j] = (f32x4){0.f,0.f,0.f,0.f};

    // -------- GEMM: K = 192 in 3 steps of 64 --------
    #pragma unroll
    for (int it = 0; it < 3; ++it){
        const int k0 = it * 64;
        __syncthreads();
        // A tile: 96 rows x 64 k, gathered on the fly (x | xn | e48)
        for (int e = tid; e < 768; e += TPB){
            int r  = e >> 3;
            int kk = (e & 7) << 3;
            int grow = row0 + r;
            float v[8];
            #pragma unroll
            for (int q2=0;q2<8;q2++) v[q2] = 0.f;
            if (it == 2){
                if (kk < LDE){
                    const float* s = E48 + (size_t)grow*LDE + kk;
                    float4 a0 = *(const float4*)s;
                    float4 a1 = *(const float4*)(s+4);
                    v[0]=a0.x; v[1]=a0.y; v[2]=a0.z; v[3]=a0.w;
                    v[4]=a1.x; v[5]=a1.y; v[6]=a1.z; v[7]=a1.w;
                }
            } else {
                const float* s = (it == 0)
                    ? X + (size_t)(atomBase + r/12)*AF + kk
                    : X + (size_t)idx[grow]*AF + kk;
                float4 a0 = *(const float4*)s;
                float4 a1 = *(const float4*)(s+4);
                v[0]=a0.x; v[1]=a0.y; v[2]=a0.z; v[3]=a0.w;
                v[4]=a1.x; v[5]=a1.y; v[6]=a1.z; v[7]=a1.w;
            }
            *(uint4*)(&As[r][kk]) = pack_bf16_8(v);
        }
        // W tile: 512 cols x 64 k (pre-packed bf16, L2-resident)
        for (int e = tid; e < 4096; e += TPB){
            int r  = e >> 3;
            int kk = (e & 7) << 3;
            *(uint4*)(&Ws[r][kk]) = *(const uint4*)(W + (size_t)r*LDA_T + k0 + kk);
        }
        __syncthreads();
        #pragma unroll
        for (int ks = 0; ks < 2; ++ks){
            int koff = ks*32 + quad*8;
            bf16x8 a_[3], b_[8];
            #pragma unroll
            for (int mi=0;mi<3;mi++)
                a_[mi] = *(const bf16x8*)(&As[wm*48 + mi*16 + lrow][koff]);
            #pragma unroll
            for (int ni=0;ni<8;ni++)
                b_[ni] = *(const bf16x8*)(&Ws[cg*128 + ni*16 + lrow][koff]);
            #pragma unroll
            for (int mi=0;mi<3;mi++)
                #pragma unroll
                for (int ni=0;ni<8;ni++)
                    acc[mi][ni] = __builtin_amdgcn_mfma_f32_16x16x32_bf16(
                        a_[mi], b_[ni], acc[mi][ni], 0, 0, 0);
        }
    }

    __syncthreads();
    // -------- dump h/he (cols 0..255, +bias) to LDS; column stats --------
    if (cg < 2){
        #pragma unroll
        for (int mi=0;mi<3;mi++)
            #pragma unroll
            for (int ni=0;ni<8;ni++){
                int cl = cg*128 + ni*16 + lrow;
                float bv = bL[cl];
                #pragma unroll
                for (int reg=0;reg<4;reg++){
                    int rl = wm*48 + mi*16 + quad*4 + reg;
                    HPQ[rl][cl] = acc[mi][ni][reg] + bv;
                }
            }
    }
    __syncthreads();
    if (tid < 256){
        float s1 = 0.f, s2 = 0.f;
        for (int r = 0; r < 96; ++r){
            float v = HPQ[r][tid];
            s1 += v; s2 += v*v;
        }
        atomicAdd(&STL[tid],       s1);
        atomicAdd(&STL[256 + tid], s2);
    }
    __syncthreads();
    // -------- dump P'/Q' (cols 256..511, +bias) to LDS; 3-body stats --------
    if (cg >= 2){
        #pragma unroll
        for (int mi=0;mi<3;mi++)
            #pragma unroll
            for (int ni=0;ni<8;ni++){
                int cl = (cg-2)*128 + ni*16 + lrow;
                float bv = bL[256 + cl];
                #pragma unroll
                for (int reg=0;reg<4;reg++){
                    int rl = wm*48 + mi*16 + quad*4 + reg;
                    HPQ[rl][cl] = acc[mi][ni][reg] + bv;
                }
            }
    }
    __syncthreads();
    // per-atom channel sums: local cols [0..127]=P', [128..255]=Q'
    for (int item = tid; item < 1024; item += TPB){
        int n = item >> 7, c = item & 127;
        int r0 = n * MNBR;
        float sp=0.f, spp=0.f, sq=0.f, sqq=0.f;
        #pragma unroll
        for (int m=0;m<MNBR;m++){
            float p = HPQ[r0+m][c];
            float q = HPQ[r0+m][128+c];
            sp += p; spp += p*p; sq += q; sqq += q*q;
        }
        atomicAdd(&s13L[c], 12.f*(sp+sq));
        atomicAdd(&s23L[c], 12.f*(spp+sqq) + 2.f*sp*sq);
    }
    __syncthreads();
    if (tid < 128){
        atomicAdd(&STL[512 + tid], s13L[tid]);
        atomicAdd(&STL[640 + tid], s23L[tid]);
    }

    gridbar(bar, NBLK);   // ---- all BN stats complete device-wide ----

    // -------- BN finalize (each block, in LDS) --------
    if (tid < 256){
        int c = tid;
        if (c < O1+OE){
            float mean = aloadf(&STL[c]) * (1.f/NM);
            float var  = fmaxf(aloadf(&STL[256+c])*(1.f/NM) - mean*mean, 0.f);
            float gg = (c < O1) ? g1[c] : ge[c-O1];
            float bb = (c < O1) ? b1[c] : be[c-O1];
            float sc = gg * rsqrtf(var + EPS_BN);
            scT[c] = sc; shT[c] = bb - sc*mean;
        }
    } else if (tid < 384){
        int c = tid - 256;
        float inv  = 1.f/((float)NM*MNBR);
        float mean = aloadf(&STL[512+c]) * inv;
        float var  = fmaxf(aloadf(&STL[640+c])*inv - mean*mean, 0.f);
        float sc = g3[c] * rsqrtf(var + EPS_BN);
        sc3[c] = sc; sh3[c] = b3b[c] - sc*mean;
    }
    __syncthreads();

    // -------- 3-body: wave = atom, lane = channel a --------
    const int r0a = w * MNBR;
    float acc3 = 0.f;
    {
        float s3lo = sc3[l],    t3lo = sh3[l];
        float s3hi = sc3[64+l], t3hi = sh3[64+l];
        float Qa[MNBR], Qb[MNBR], ua[MNBR], ub[MNBR];
        #pragma unroll
        for (int m=0;m<MNBR;m++){
            Qa[m] = s3lo*HPQ[r0a+m][128+l];
            Qb[m] = s3hi*HPQ[r0a+m][192+l];
            ua[m] = s3lo*HPQ[r0a+m][l]      + t3lo;
            ub[m] = s3hi*HPQ[r0a+m][64+l]   + t3hi;
        }
        #pragma unroll
        for (int m=0;m<MNBR;m++)
            #pragma unroll
            for (int l2=0;l2<MNBR;l2++)
                acc3 += sigmoidf_(ua[m]+Qa[l2]) * softplusf_(ub[m]+Qb[l2]);
    }
    __syncthreads();
    // -------- re-dump h/he from registers (acc still live) --------
    if (cg < 2){
        #pragma unroll
        for (int mi=0;mi<3;mi++)
            #pragma unroll
            for (int ni=0;ni<8;ni++){
                int cl = cg*128 + ni*16 + lrow;
                float bv = bL[cl];
                #pragma unroll
                for (int reg=0;reg<4;reg++){
                    int rl = wm*48 + mi*16 + quad*4 + reg;
                    HPQ[rl][cl] = acc[mi][ni][reg] + bv;
                }
            }
    }
    __syncthreads();
    // -------- 2-body + TB; edge update --------
    {
        float sha = scT[l],    tha = shT[l];
        float shb = scT[64+l], thb = shT[64+l];
        float acc2 = 0.f;
        #pragma unroll
        for (int m=0;m<MNBR;m++)
            acc2 += sigmoidf_(sha*HPQ[r0a+m][l]+tha) * softplusf_(shb*HPQ[r0a+m][64+l]+thb);
        tbL[tid] = acc2 + acc3;
    }
    for (int item = tid; item < 8*MNBR*BFEA; item += TPB){
        int n = item / (MNBR*BFEA);
        int rem = item % (MNBR*BFEA);
        int m = rem / BFEA, b = rem % BFEA;
        const float* hr = HPQ[n*MNBR + m];
        float u = scT[O1+b]*hr[O1+b]   + shT[O1+b];
        float vv = scT[169+b]*hr[169+b] + shT[169+b];
        E48[((size_t)(atomBase+n)*MNBR + m)*LDE + b] += sigmoidf_(u) * softplusf_(vv);
    }
    __syncthreads();
    if (tid < 64){
        float s1 = 0.f, s2 = 0.f;
        #pragma unroll
        for (int n=0;n<8;n++){
            float v = tbL[n*64 + tid];
            s1 += v; s2 += v*v;
        }
        atomicAdd(&STL[768 + tid], s1);
        atomicAdd(&STL[832 + tid], s2);
    }

    gridbar(bar, NBLK);   // ---- TB stats complete device-wide ----

    // -------- x = softplus(x + bn2(TB)) for own 8 atoms --------
    {
        int n = tid >> 6, a2 = tid & 63;
        float mean = aloadf(&STL[768+a2]) * (1.f/N_ATOM);
        float var  = fmaxf(aloadf(&STL[832+a2])*(1.f/N_ATOM) - mean*mean, 0.f);
        float sc = g2[a2]*rsqrtf(var + EPS_BN);
        size_t gx = (size_t)(atomBase+n)*AF + a2;
        X[gx] = softplusf_(X[gx] + sc*tbL[tid] + (b2[a2] - sc*mean));
    }
}

// ================= small fp32 GEMM (embedding / head)
#define BM 64
#define BN 128
#define BK 32
template<int EPI, int SPIN>
__global__ __launch_bounds__(256)
void gemm_tn(const float* __restrict__ T, int ldt, int R,
             const float* __restrict__ W, int ldw, int K, int O,
             const float* __restrict__ bias,
             float* __restrict__ C, int ldc)
{
    __shared__ float Ts[BM][BK+1];
    __shared__ float Ws2[BN][BK+1];
    const int tid = threadIdx.x;
    const int row0 = blockIdx.x * BM;
    const int tx = tid % 16;
    const int ty = tid / 16;
    float acc[4][8];
    #pragma unroll
    for (int i=0;i<4;i++)
        #pragma unroll
        for (int j=0;j<8;j++) acc[i][j]=0.f;

    for (int k0 = 0; k0 < K; k0 += BK) {
        #pragma unroll
        for (int i=0;i<(BM*BK)/256;i++){
            int e = tid + i*256;
            int r = e / BK, k = e % BK;
            int gr = row0 + r, gk = k0 + k;
            float v = 0.f;
            if (gr < R && gk < K){
                v = T[(size_t)gr*ldt + gk];
                if (SPIN) v = softplusf_(v);
            }
            Ts[r][k] = v;
        }
        #pragma unroll
        for (int i=0;i<(BN*BK)/256;i++){
            int e = tid + i*256;
            int r = e / BK, k = e % BK;
            int gk = k0 + k;
            Ws2[r][k] = (r < O && gk < K) ? W[(size_t)r*ldw + gk] : 0.f;
        }
        __syncthreads();
        #pragma unroll
        for (int k=0;k<BK;k++){
            float a_[4], b_[8];
            #pragma unroll
            for (int i=0;i<4;i++) a_[i] = Ts[ty*4+i][k];
            #pragma unroll
            for (int j=0;j<8;j++) b_[j] = Ws2[tx + j*16][k];
            #pragma unroll
            for (int i=0;i<4;i++)
                #pragma unroll
                for (int j=0;j<8;j++)
                    acc[i][j] += a_[i]*b_[j];
        }
        __syncthreads();
    }
    #pragma unroll
    for (int i=0;i<4;i++){
        int gr = row0 + ty*4 + i;
        if (gr >= R) continue;
        #pragma unroll
        for (int j=0;j<8;j++){
            int gc = tx + j*16;
            if (gc >= O) continue;
            float v = acc[i][j] + (bias ? bias[gc] : 0.f);
            if (EPI==1) v = softplusf_(v);
            C[(size_t)gr*ldc + gc] = v;
        }
    }
}

// ================= pack weights (bf16) + bias (fp32).
__global__ void pack_all(const float* __restrict__ fcW, const float* __restrict__ eW,
                         const float* __restrict__ W3, const float* __restrict__ fcb,
                         const float* __restrict__ eb, const float* __restrict__ b3,
                         __hip_bfloat16* __restrict__ WALL, float* __restrict__ BIAS)
{
    int i = blockIdx.x*blockDim.x + threadIdx.x;
    const int nW = NCONV*512*LDA_T;
    if (i < nW){
        int ll = i/(512*LDA_T), rem = i%(512*LDA_T);
        int c = rem/LDA_T, k = rem%LDA_T;
        float v = 0.f;
        if (c < O1){
            if (k < K1) v = fcW[((size_t)ll*O1 + c)*K1 + k];
        } else if (c < O1+OE){
            if (k < K1) v = eW[((size_t)ll*OE + (c-O1))*K1 + k];
        } else if (c >= 256 && c < 384){
            int o = c - 256;
            const float* W3l = W3 + (size_t)ll*O1*274;
            if (k < AF)                        v = 0.5f * W3l[(size_t)o*274 + k];          // Wa/2
            else if (k < 2*AF)                 v = W3l[(size_t)o*274 + k];                 // Wj
            else if (k < K1)                   v = W3l[(size_t)o*274 + 192 + (k-128)];     // Wij
        } else if (c >= 384){
            int o = c - 384;
            const float* W3l = W3 + (size_t)ll*O1*274;
            if (k < AF)                        v = 0.5f * W3l[(size_t)o*274 + k];          // Wa/2
            else if (k < 2*AF)                 v = W3l[(size_t)o*274 + k + AF];            // Wl
            else if (k < K1)                   v = W3l[(size_t)o*274 + 233 + (k-128)];     // Wil
        }
        WALL[i] = __float2bfloat16(v);
    } else if (i < nW + NCONV*512){
        int m = i - nW;
        int ll = m/512, c = m%512;
        float v = 0.f;
        if (c < O1)         v = fcb[ll*O1 + c];
        else if (c < O1+OE) v = eb[ll*OE + (c-O1)];
        else if (c >= 256)  v = 0.5f * b3[ll*O1 + ((c-256)&127)];
        BIAS[m] = v;
    }
}

// ================= nbr_fea [NM][41] -> E48 [NM][48] (zero-padded)
__global__ void e_init(const float* __restrict__ nbr, float* __restrict__ E48)
{
    int i = blockIdx.x*blockDim.x + threadIdx.x;
    if (i >= NM*LDE) return;
    int r = i / LDE, k = i % LDE;
    E48[i] = (k < BFEA) ? nbr[(size_t)r*BFEA + k] : 0.f;
}

// ================= pooled mean per crystal + final dot
__global__ __launch_bounds__(128)
void pool_out_k(const float* __restrict__ Z, const int* __restrict__ seg,
                const float* __restrict__ outW, const float* __restrict__ outb,
                float* __restrict__ out)
{
    __shared__ float red[128];
    const int c = blockIdx.x;
    const int h = threadIdx.x;
    int l0, l1;
    {
        int l=0, r=N_ATOM;
        while (l<r){ int m=(l+r)>>1; if (seg[m] < c) l=m+1; else r=m; }
        l0 = l;
        l=l0; r=N_ATOM;
        while (l<r){ int m=(l+r)>>1; if (seg[m] < c+1) l=m+1; else r=m; }
        l1 = l;
    }
    float s = 0.f;
    for (int n = l0; n < l1; ++n) s += Z[(size_t)n*HID + h];
    float cnt = fmaxf((float)(l1-l0), 1.f);
    red[h] = (s/cnt) * outW[h];
    __syncthreads();
    for (int off=64; off>0; off>>=1){
        if (h < off) red[h] += red[h+off];
        __syncthreads();
    }
    if (h == 0) out[c] = red[0] + outb[0];
}

extern "C" void kernel_launch(void* const* d_in, const int* in_sizes, int n_in,
                              void* d_out, int out_size, void* d_ws, size_t ws_size,
                              hipStream_t stream)
{
    const float* atom_fea = (const float*)d_in[0];
    const float* nbr_fea  = (const float*)d_in[1];
    const int*   nbr_idx  = (const int*)d_in[2];
    const int*   site_seg = (const int*)d_in[3];
    const float* emb_W = (const float*)d_in[4];
    const float* emb_b = (const float*)d_in[5];
    const float* fcW   = (const float*)d_in[6];
    const float* fcb   = (const float*)d_in[7];
    const float* bn1_g = (const float*)d_in[8];
    const float* bn1_b = (const float*)d_in[9];
    const float* bn2_g = (const float*)d_in[10];
    const float* bn2_b = (const float*)d_in[11];
    const float* eW    = (const float*)d_in[12];
    const float* eb    = (const float*)d_in[13];
    const float* bne_g = (const float*)d_in[14];
    const float* bne_b = (const float*)d_in[15];
    const float* W3    = (const float*)d_in[16];
    const float* b3    = (const float*)d_in[17];
    const float* bn3_g = (const float*)d_in[18];
    const float* bn3_b = (const float*)d_in[19];
    const float* fc1W  = (const float*)d_in[20];
    const float* fc1b  = (const float*)d_in[21];
    const float* outW  = (const float*)d_in[22];
    const float* outb  = (const float*)d_in[23];

    // workspace layout (float units)
    float* ws   = (float*)d_ws;
    float* X    = ws;                         // 128,000
    float* E48  = ws + 128000;                // 1,152,000 -> 1,280,000
    float* Z    = ws + 1280000;               // 256,000   -> 1,536,000
    float* ST   = ws + 1536000;               // 3*2048    -> 1,542,144
    unsigned* BAR = (unsigned*)(ws + 1542144);// 16        -> 1,542,160
    __hip_bfloat16* WALL = (__hip_bfloat16*)(ws + 1542160); // 294,912 bf16 -> +147,456
    float* BIAS = ws + 1689616;               // 1,536

    static int s_attr = 0;
    if (!s_attr){
        hipFuncSetAttribute((const void*)mega_k,
                            hipFuncAttributeMaxDynamicSharedMemorySize, DYN_LDS);
        s_attr = 1;
    }

    {
        int tot = NCONV*512*LDA_T + NCONV*512;
        pack_all<<<(tot+255)/256, 256, 0, stream>>>(fcW, eW, W3, fcb, eb, b3, WALL, BIAS);
    }
    hipMemsetAsync(ST, 0, (size_t)(6144 + 16) * sizeof(float), stream);
    gemm_tn<0,0><<<(N_ATOM+BM-1)/BM, 256, 0, stream>>>(atom_fea, OFEA, N_ATOM,
                                                       emb_W, OFEA, OFEA, AF, emb_b, X, AF);
    e_init<<<(NM*LDE+255)/256, 256, 0, stream>>>(nbr_fea, E48);

    for (int i = 0; i < NCONV; i++){
        mega_k<<<NBLK, TPB, DYN_LDS, stream>>>(
            X, E48, nbr_idx,
            WALL + (size_t)i*512*LDA_T, BIAS + i*512,
            ST + i*2048, BAR,
            bn1_g + i*O1, bn1_b + i*O1,
            bne_g + i*OE, bne_b + i*OE,
            bn3_g + i*O1, bn3_b + i*O1,
            bn2_g + i*AF, bn2_b + i*AF);
    }

    // head: Z = softplus(softplus(X) @ fc1W^T + fc1b); pooled mean; out
    gemm_tn<1,1><<<(N_ATOM+BM-1)/BM, 256, 0, stream>>>(X, AF, N_ATOM, fc1W, AF, AF, HID,
                                                       fc1b, Z, HID);
    pool_out_k<<<NCRY, 128, 0, stream>>>(Z, site_seg, outW, outb, (float*)d_out);
}

// Round 3
// 504.671 us; speedup vs baseline: 2.0693x; 2.0693x over previous
//
#include <hip/hip_runtime.h>
#include <hip/hip_bf16.h>

// Problem constants
#define N_ATOM 2000
#define MNBR   12
#define OFEA   92
#define AF     64
#define BFEA   41
#define K1     169   // 2A+B
#define O1     128
#define OE     82
#define NM     24000
#define NCONV  3
#define HID    128
#define NCRY   64
#define EPS_BN 1e-5f

#define LDA_T  192   // bf16 weight leading dim (169 padded to 192)
#define LDSW   88    // LDS row pitch (ushorts) for MFMA tiles
#define LDE    48    // padded E stride (41 -> 48, float4-aligned rows)
#define LDP    260   // PQf row pitch (floats)
#define LDHB   212   // Hbuf row pitch (floats), 210 used
#define TPB    512
#define NBLK   250   // 24000 rows / 96 rows-per-block (exact)

typedef __bf16 bf16x8 __attribute__((ext_vector_type(8)));
typedef float  f32x4  __attribute__((ext_vector_type(4)));

// -------- dynamic LDS layout (bytes) --------
// [0, 107008): GEMM phase As[96][88]+Ws[512][88]  /  consumer phase PQf[96][260] (99840)
#define AS_OFF    0
#define WS_OFF    16896
#define PQ_OFF    0
#define BL_OFF    107008       // float bL[512]    = 2048
#define CSA_OFF   109056       // float csA[256]   = 1024
#define CSB_OFF   110080       // float csB[256]   = 1024
#define SCT_OFF   111104       // float scT[256]   = 1024
#define SHT_OFF   112128       // float shT[256]   = 1024
#define SC3_OFF   113152       // float sc3[128]   = 512
#define SH3_OFF   113664       // float sh3[128]   = 512
#define S13_OFF   114176       // float s13L[128]  = 512
#define S23_OFF   114688       // float s23L[128]  = 512
#define TBL_OFF   115200       // float tbL[512]   = 2048
#define DYN_LDS   117248

__device__ __forceinline__ float sigmoidf_(float x){
    return __builtin_amdgcn_rcpf(1.f + __expf(-x));
}
__device__ __forceinline__ float softplusf_(float x){
    return fmaxf(x,0.f) + __logf(1.f + __expf(-fabsf(x)));
}
__device__ __forceinline__ uint4 pack_bf16_8(const float* v){
    __hip_bfloat16 o[8];
    #pragma unroll
    for (int j=0;j<8;j++) o[j] = __float2bfloat16(v[j]);
    return *(const uint4*)o;
}
__device__ __forceinline__ float aloadf(const float* p){
    return __hip_atomic_load((float*)p, __ATOMIC_RELAXED, __HIP_MEMORY_SCOPE_AGENT);
}

// software grid barrier: bar[0]=cnt, bar[1]=gen (zeroed before first launch)
__device__ __forceinline__ void gridbar(unsigned* bar, unsigned target){
    __syncthreads();
    if (threadIdx.x == 0){
        unsigned* cnt = bar;
        unsigned* gen = bar + 1;
        unsigned g = __hip_atomic_load(gen, __ATOMIC_RELAXED, __HIP_MEMORY_SCOPE_AGENT);
        unsigned a = __hip_atomic_fetch_add(cnt, 1u, __ATOMIC_ACQ_REL, __HIP_MEMORY_SCOPE_AGENT);
        if (a + 1 == target){
            __hip_atomic_store(cnt, 0u, __ATOMIC_RELAXED, __HIP_MEMORY_SCOPE_AGENT);
            __hip_atomic_fetch_add(gen, 1u, __ATOMIC_RELEASE, __HIP_MEMORY_SCOPE_AGENT);
        } else {
            while (__hip_atomic_load(gen, __ATOMIC_ACQUIRE, __HIP_MEMORY_SCOPE_AGENT) == g)
                __builtin_amdgcn_s_sleep(4);
        }
    }
    __syncthreads();
}

// ============================================================================
// MEGA: one kernel per conv layer. Block = 8 atoms (96 rows) x all 512 cols.
// GEMM -> dump (P/Q->LDS fp32, h/he->Hbuf fp32, stats from regs) -> gridbar ->
// BN finalize -> 3-body from LDS, 2-body/edge from Hbuf -> TB stats ->
// gridbar -> x update. acc registers die at the dump: no spill.
// STL: S1A[0..255] S2A[256..511] S13[512..639] S23[640..767] S12[768..831] S22[832..895]
// ============================================================================
__global__ __launch_bounds__(TPB)
void mega_k(float* __restrict__ X, float* __restrict__ E48,
            float* __restrict__ Hbuf,
            const int* __restrict__ idx,
            const __hip_bfloat16* __restrict__ W, const float* __restrict__ bias,
            float* __restrict__ STL, unsigned* __restrict__ bar,
            const float* __restrict__ g1, const float* __restrict__ b1,
            const float* __restrict__ ge, const float* __restrict__ be,
            const float* __restrict__ g3, const float* __restrict__ b3b,
            const float* __restrict__ g2, const float* __restrict__ b2)
{
    extern __shared__ char smem[];
    unsigned short (*As)[LDSW] = (unsigned short(*)[LDSW])(smem + AS_OFF);
    unsigned short (*Ws)[LDSW] = (unsigned short(*)[LDSW])(smem + WS_OFF);
    float (*PQf)[LDP] = (float(*)[LDP])(smem + PQ_OFF);
    float* bL   = (float*)(smem + BL_OFF);
    float* csA  = (float*)(smem + CSA_OFF);
    float* csB  = (float*)(smem + CSB_OFF);
    float* scT  = (float*)(smem + SCT_OFF);
    float* shT  = (float*)(smem + SHT_OFF);
    float* sc3  = (float*)(smem + SC3_OFF);
    float* sh3  = (float*)(smem + SH3_OFF);
    float* s13L = (float*)(smem + S13_OFF);
    float* s23L = (float*)(smem + S23_OFF);
    float* tbL  = (float*)(smem + TBL_OFF);

    const int tid = threadIdx.x;
    const int w    = tid >> 6;
    const int l    = tid & 63;
    const int wm   = w >> 2;      // 0..1 row half (48 rows each)
    const int cg   = w & 3;       // 0..3 col group (128 cols each)
    const int lrow = l & 15;
    const int quad = l >> 4;
    const int row0 = blockIdx.x * 96;
    const int atomBase = blockIdx.x * 8;

    bL[tid] = bias[tid];
    if (tid < 256){ csA[tid] = 0.f; csB[tid] = 0.f; }
    if (tid < 128){ s13L[tid] = 0.f; s23L[tid] = 0.f; }

    f32x4 acc[3][8];
    #pragma unroll
    for (int i=0;i<3;i++)
        #pragma unroll
        for (int j=0;j<8;j++) acc[i][j] = (f32x4){0.f,0.f,0.f,0.f};

    // -------- GEMM: K = 192 in 3 steps of 64 --------
    #pragma unroll
    for (int it = 0; it < 3; ++it){
        const int k0 = it * 64;
        __syncthreads();
        // A tile: 96 rows x 64 k, gathered on the fly (x | xn | e48)
        for (int e = tid; e < 768; e += TPB){
            int r  = e >> 3;
            int kk = (e & 7) << 3;
            int grow = row0 + r;
            float v[8];
            #pragma unroll
            for (int q2=0;q2<8;q2++) v[q2] = 0.f;
            if (it == 2){
                if (kk < LDE){
                    const float* s = E48 + (size_t)grow*LDE + kk;
                    float4 a0 = *(const float4*)s;
                    float4 a1 = *(const float4*)(s+4);
                    v[0]=a0.x; v[1]=a0.y; v[2]=a0.z; v[3]=a0.w;
                    v[4]=a1.x; v[5]=a1.y; v[6]=a1.z; v[7]=a1.w;
                }
            } else {
                const float* s = (it == 0)
                    ? X + (size_t)(atomBase + r/12)*AF + kk
                    : X + (size_t)idx[grow]*AF + kk;
                float4 a0 = *(const float4*)s;
                float4 a1 = *(const float4*)(s+4);
                v[0]=a0.x; v[1]=a0.y; v[2]=a0.z; v[3]=a0.w;
                v[4]=a1.x; v[5]=a1.y; v[6]=a1.z; v[7]=a1.w;
            }
            *(uint4*)(&As[r][kk]) = pack_bf16_8(v);
        }
        // W tile: 512 cols x 64 k (pre-packed bf16, L2-resident)
        for (int e = tid; e < 4096; e += TPB){
            int r  = e >> 3;
            int kk = (e & 7) << 3;
            *(uint4*)(&Ws[r][kk]) = *(const uint4*)(W + (size_t)r*LDA_T + k0 + kk);
        }
        __syncthreads();
        #pragma unroll
        for (int ks = 0; ks < 2; ++ks){
            int koff = ks*32 + quad*8;
            bf16x8 a_[3], b_[8];
            #pragma unroll
            for (int mi=0;mi<3;mi++)
                a_[mi] = *(const bf16x8*)(&As[wm*48 + mi*16 + lrow][koff]);
            #pragma unroll
            for (int ni=0;ni<8;ni++)
                b_[ni] = *(const bf16x8*)(&Ws[cg*128 + ni*16 + lrow][koff]);
            #pragma unroll
            for (int mi=0;mi<3;mi++)
                #pragma unroll
                for (int ni=0;ni<8;ni++)
                    acc[mi][ni] = __builtin_amdgcn_mfma_f32_16x16x32_bf16(
                        a_[mi], b_[ni], acc[mi][ni], 0, 0, 0);
        }
    }

    __syncthreads();   // As/Ws dead from here; PQf takes over the region

    // -------- dump: h/he -> Hbuf (+reg stats), P'/Q' -> LDS fp32 --------
    if (cg < 2){
        #pragma unroll
        for (int ni=0;ni<8;ni++){
            int cl = cg*128 + ni*16 + lrow;     // 0..255
            float bv = bL[cl];
            float s1 = 0.f, s2 = 0.f;
            #pragma unroll
            for (int mi=0;mi<3;mi++){
                #pragma unroll
                for (int reg=0;reg<4;reg++){
                    int rl = wm*48 + mi*16 + quad*4 + reg;
                    float vv = acc[mi][ni][reg] + bv;
                    if (cl < 210)
                        Hbuf[(size_t)(row0+rl)*LDHB + cl] = vv;
                    s1 += vv; s2 += vv*vv;
                }
            }
            if (cl < 210){
                atomicAdd(&csA[cl], s1);
                atomicAdd(&csB[cl], s2);
            }
        }
    } else {
        #pragma unroll
        for (int ni=0;ni<8;ni++){
            int cl = (cg-2)*128 + ni*16 + lrow; // 0..127 P', 128..255 Q'
            float bv = bL[256 + cl];
            #pragma unroll
            for (int mi=0;mi<3;mi++)
                #pragma unroll
                for (int reg=0;reg<4;reg++){
                    int rl = wm*48 + mi*16 + quad*4 + reg;
                    PQf[rl][cl] = acc[mi][ni][reg] + bv;
                }
        }
    }
    __syncthreads();

    // -------- block-local stats -> global STL --------
    if (tid < 210){
        atomicAdd(&STL[tid],       csA[tid]);
        atomicAdd(&STL[256 + tid], csB[tid]);
    }
    for (int item = tid; item < 1024; item += TPB){
        int n = item >> 7, c = item & 127;
        int r0 = n * MNBR;
        float sp=0.f, spp=0.f, sq=0.f, sqq=0.f;
        #pragma unroll
        for (int m=0;m<MNBR;m++){
            float p = PQf[r0+m][c];
            float q = PQf[r0+m][128+c];
            sp += p; spp += p*p; sq += q; sqq += q*q;
        }
        atomicAdd(&s13L[c], 12.f*(sp+sq));
        atomicAdd(&s23L[c], 12.f*(spp+sqq) + 2.f*sp*sq);
    }
    __syncthreads();
    if (tid < 128){
        atomicAdd(&STL[512 + tid], s13L[tid]);
        atomicAdd(&STL[640 + tid], s23L[tid]);
    }

    gridbar(bar, NBLK);   // ---- all BN stats complete device-wide ----

    // -------- BN finalize (per block, into LDS) --------
    if (tid < 210){
        float mean = aloadf(&STL[tid]) * (1.f/NM);
        float var  = fmaxf(aloadf(&STL[256+tid])*(1.f/NM) - mean*mean, 0.f);
        float gg = (tid < O1) ? g1[tid] : ge[tid-O1];
        float bb = (tid < O1) ? b1[tid] : be[tid-O1];
        float sc = gg * rsqrtf(var + EPS_BN);
        scT[tid] = sc; shT[tid] = bb - sc*mean;
    } else if (tid >= 256 && tid < 384){
        int c = tid - 256;
        float inv  = 1.f/((float)NM*MNBR);
        float mean = aloadf(&STL[512+c]) * inv;
        float var  = fmaxf(aloadf(&STL[640+c])*inv - mean*mean, 0.f);
        float sc = g3[c] * rsqrtf(var + EPS_BN);
        sc3[c] = sc; sh3[c] = b3b[c] - sc*mean;
    }
    __syncthreads();

    // -------- 3-body: wave = atom, lane = channel --------
    const int r0a = w * MNBR;
    float acc3 = 0.f;
    {
        float s3lo = sc3[l],    t3lo = sh3[l];
        float s3hi = sc3[64+l], t3hi = sh3[64+l];
        float Qa[MNBR], Qb[MNBR], ua[MNBR], ub[MNBR];
        #pragma unroll
        for (int m=0;m<MNBR;m++){
            ua[m] = s3lo*PQf[r0a+m][l]      + t3lo;
            ub[m] = s3hi*PQf[r0a+m][64+l]   + t3hi;
            Qa[m] = s3lo*PQf[r0a+m][128+l];
            Qb[m] = s3hi*PQf[r0a+m][192+l];
        }
        #pragma unroll
        for (int m=0;m<MNBR;m++)
            #pragma unroll
            for (int l2=0;l2<MNBR;l2++)
                acc3 += sigmoidf_(ua[m]+Qa[l2]) * softplusf_(ub[m]+Qb[l2]);
    }
    // -------- 2-body from Hbuf (own rows, L2-hot) --------
    {
        const float* hb = Hbuf + (size_t)(row0 + w*MNBR)*LDHB;
        float sha = scT[l],    tha = shT[l];
        float shb = scT[64+l], thb = shT[64+l];
        float acc2 = 0.f;
        #pragma unroll
        for (int m=0;m<MNBR;m++)
            acc2 += sigmoidf_(sha*hb[m*LDHB + l] + tha)
                  * softplusf_(shb*hb[m*LDHB + 64 + l] + thb);
        tbL[tid] = acc2 + acc3;
    }
    // -------- edge update (own rows) --------
    for (int item = tid; item < 8*MNBR*BFEA; item += TPB){
        int n = item / (MNBR*BFEA);
        int rem = item % (MNBR*BFEA);
        int m = rem / BFEA, b = rem % BFEA;
        const float* hr = Hbuf + (size_t)(row0 + n*MNBR + m)*LDHB;
        float u  = scT[O1+b]*hr[O1+b]   + shT[O1+b];
        float vv = scT[169+b]*hr[169+b] + shT[169+b];
        E48[((size_t)(atomBase+n)*MNBR + m)*LDE + b] += sigmoidf_(u) * softplusf_(vv);
    }
    __syncthreads();
    if (tid < 64){
        float s1 = 0.f, s2 = 0.f;
        #pragma unroll
        for (int n=0;n<8;n++){
            float v = tbL[n*64 + tid];
            s1 += v; s2 += v*v;
        }
        atomicAdd(&STL[768 + tid], s1);
        atomicAdd(&STL[832 + tid], s2);
    }

    gridbar(bar, NBLK);   // ---- TB stats complete device-wide ----

    // -------- x = softplus(x + bn2(TB)) for own 8 atoms --------
    {
        int n = tid >> 6, a2 = tid & 63;
        float mean = aloadf(&STL[768+a2]) * (1.f/N_ATOM);
        float var  = fmaxf(aloadf(&STL[832+a2])*(1.f/N_ATOM) - mean*mean, 0.f);
        float sc = g2[a2]*rsqrtf(var + EPS_BN);
        size_t gx = (size_t)(atomBase+n)*AF + a2;
        X[gx] = softplusf_(X[gx] + sc*tbL[tid] + (b2[a2] - sc*mean));
    }
}

// ================= small fp32 GEMM (embedding / head)
#define BM 64
#define BN 128
#define BK 32
template<int EPI, int SPIN>
__global__ __launch_bounds__(256)
void gemm_tn(const float* __restrict__ T, int ldt, int R,
             const float* __restrict__ W, int ldw, int K, int O,
             const float* __restrict__ bias,
             float* __restrict__ C, int ldc)
{
    __shared__ float Ts[BM][BK+1];
    __shared__ float Ws2[BN][BK+1];
    const int tid = threadIdx.x;
    const int row0 = blockIdx.x * BM;
    const int tx = tid % 16;
    const int ty = tid / 16;
    float acc[4][8];
    #pragma unroll
    for (int i=0;i<4;i++)
        #pragma unroll
        for (int j=0;j<8;j++) acc[i][j]=0.f;

    for (int k0 = 0; k0 < K; k0 += BK) {
        #pragma unroll
        for (int i=0;i<(BM*BK)/256;i++){
            int e = tid + i*256;
            int r = e / BK, k = e % BK;
            int gr = row0 + r, gk = k0 + k;
            float v = 0.f;
            if (gr < R && gk < K){
                v = T[(size_t)gr*ldt + gk];
                if (SPIN) v = softplusf_(v);
            }
            Ts[r][k] = v;
        }
        #pragma unroll
        for (int i=0;i<(BN*BK)/256;i++){
            int e = tid + i*256;
            int r = e / BK, k = e % BK;
            int gk = k0 + k;
            Ws2[r][k] = (r < O && gk < K) ? W[(size_t)r*ldw + gk] : 0.f;
        }
        __syncthreads();
        #pragma unroll
        for (int k=0;k<BK;k++){
            float a_[4], b_[8];
            #pragma unroll
            for (int i=0;i<4;i++) a_[i] = Ts[ty*4+i][k];
            #pragma unroll
            for (int j=0;j<8;j++) b_[j] = Ws2[tx + j*16][k];
            #pragma unroll
            for (int i=0;i<4;i++)
                #pragma unroll
                for (int j=0;j<8;j++)
                    acc[i][j] += a_[i]*b_[j];
        }
        __syncthreads();
    }
    #pragma unroll
    for (int i=0;i<4;i++){
        int gr = row0 + ty*4 + i;
        if (gr >= R) continue;
        #pragma unroll
        for (int j=0;j<8;j++){
            int gc = tx + j*16;
            if (gc >= O) continue;
            float v = acc[i][j] + (bias ? bias[gc] : 0.f);
            if (EPI==1) v = softplusf_(v);
            C[(size_t)gr*ldc + gc] = v;
        }
    }
}

// ================= pack weights (bf16) + bias (fp32).
__global__ void pack_all(const float* __restrict__ fcW, const float* __restrict__ eW,
                         const float* __restrict__ W3, const float* __restrict__ fcb,
                         const float* __restrict__ eb, const float* __restrict__ b3,
                         __hip_bfloat16* __restrict__ WALL, float* __restrict__ BIAS)
{
    int i = blockIdx.x*blockDim.x + threadIdx.x;
    const int nW = NCONV*512*LDA_T;
    if (i < nW){
        int ll = i/(512*LDA_T), rem = i%(512*LDA_T);
        int c = rem/LDA_T, k = rem%LDA_T;
        float v = 0.f;
        if (c < O1){
            if (k < K1) v = fcW[((size_t)ll*O1 + c)*K1 + k];
        } else if (c < O1+OE){
            if (k < K1) v = eW[((size_t)ll*OE + (c-O1))*K1 + k];
        } else if (c >= 256 && c < 384){
            int o = c - 256;
            const float* W3l = W3 + (size_t)ll*O1*274;
            if (k < AF)                        v = 0.5f * W3l[(size_t)o*274 + k];          // Wa/2
            else if (k < 2*AF)                 v = W3l[(size_t)o*274 + k];                 // Wj
            else if (k < K1)                   v = W3l[(size_t)o*274 + 192 + (k-128)];     // Wij
        } else if (c >= 384){
            int o = c - 384;
            const float* W3l = W3 + (size_t)ll*O1*274;
            if (k < AF)                        v = 0.5f * W3l[(size_t)o*274 + k];          // Wa/2
            else if (k < 2*AF)                 v = W3l[(size_t)o*274 + k + AF];            // Wl
            else if (k < K1)                   v = W3l[(size_t)o*274 + 233 + (k-128)];     // Wil
        }
        WALL[i] = __float2bfloat16(v);
    } else if (i < nW + NCONV*512){
        int m = i - nW;
        int ll = m/512, c = m%512;
        float v = 0.f;
        if (c < O1)         v = fcb[ll*O1 + c];
        else if (c < O1+OE) v = eb[ll*OE + (c-O1)];
        else if (c >= 256)  v = 0.5f * b3[ll*O1 + ((c-256)&127)];
        BIAS[m] = v;
    }
}

// ================= nbr_fea [NM][41] -> E48 [NM][48] (zero-padded)
__global__ void e_init(const float* __restrict__ nbr, float* __restrict__ E48)
{
    int i = blockIdx.x*blockDim.x + threadIdx.x;
    if (i >= NM*LDE) return;
    int r = i / LDE, k = i % LDE;
    E48[i] = (k < BFEA) ? nbr[(size_t)r*BFEA + k] : 0.f;
}

// ================= pooled mean per crystal + final dot
__global__ __launch_bounds__(128)
void pool_out_k(const float* __restrict__ Z, const int* __restrict__ seg,
                const float* __restrict__ outW, const float* __restrict__ outb,
                float* __restrict__ out)
{
    __shared__ float red[128];
    const int c = blockIdx.x;
    const int h = threadIdx.x;
    int l0, l1;
    {
        int l=0, r=N_ATOM;
        while (l<r){ int m=(l+r)>>1; if (seg[m] < c) l=m+1; else r=m; }
        l0 = l;
        l=l0; r=N_ATOM;
        while (l<r){ int m=(l+r)>>1; if (seg[m] < c+1) l=m+1; else r=m; }
        l1 = l;
    }
    float s = 0.f;
    for (int n = l0; n < l1; ++n) s += Z[(size_t)n*HID + h];
    float cnt = fmaxf((float)(l1-l0), 1.f);
    red[h] = (s/cnt) * outW[h];
    __syncthreads();
    for (int off=64; off>0; off>>=1){
        if (h < off) red[h] += red[h+off];
        __syncthreads();
    }
    if (h == 0) out[c] = red[0] + outb[0];
}

extern "C" void kernel_launch(void* const* d_in, const int* in_sizes, int n_in,
                              void* d_out, int out_size, void* d_ws, size_t ws_size,
                              hipStream_t stream)
{
    const float* atom_fea = (const float*)d_in[0];
    const float* nbr_fea  = (const float*)d_in[1];
    const int*   nbr_idx  = (const int*)d_in[2];
    const int*   site_seg = (const int*)d_in[3];
    const float* emb_W = (const float*)d_in[4];
    const float* emb_b = (const float*)d_in[5];
    const float* fcW   = (const float*)d_in[6];
    const float* fcb   = (const float*)d_in[7];
    const float* bn1_g = (const float*)d_in[8];
    const float* bn1_b = (const float*)d_in[9];
    const float* bn2_g = (const float*)d_in[10];
    const float* bn2_b = (const float*)d_in[11];
    const float* eW    = (const float*)d_in[12];
    const float* eb    = (const float*)d_in[13];
    const float* bne_g = (const float*)d_in[14];
    const float* bne_b = (const float*)d_in[15];
    const float* W3    = (const float*)d_in[16];
    const float* b3    = (const float*)d_in[17];
    const float* bn3_g = (const float*)d_in[18];
    const float* bn3_b = (const float*)d_in[19];
    const float* fc1W  = (const float*)d_in[20];
    const float* fc1b  = (const float*)d_in[21];
    const float* outW  = (const float*)d_in[22];
    const float* outb  = (const float*)d_in[23];

    // workspace layout (float units)
    float* ws   = (float*)d_ws;
    float* X    = ws;                          // 128,000
    float* E48  = ws + 128000;                 // 1,152,000 -> 1,280,000
    float* Hbuf = ws + 1280000;                // 24000*212 = 5,088,000 -> 6,368,000
    float* Z    = ws + 6368000;                // 256,000 -> 6,624,000
    float* ST   = ws + 6624000;                // 3*2048  -> 6,630,144
    unsigned* BAR = (unsigned*)(ws + 6630144); // 16      -> 6,630,160
    __hip_bfloat16* WALL = (__hip_bfloat16*)(ws + 6630160); // 294,912 bf16 -> 6,777,616
    float* BIAS = ws + 6777616;                // 1,536

    static int s_attr = 0;
    if (!s_attr){
        hipFuncSetAttribute((const void*)mega_k,
                            hipFuncAttributeMaxDynamicSharedMemorySize, DYN_LDS);
        s_attr = 1;
    }

    {
        int tot = NCONV*512*LDA_T + NCONV*512;
        pack_all<<<(tot+255)/256, 256, 0, stream>>>(fcW, eW, W3, fcb, eb, b3, WALL, BIAS);
    }
    hipMemsetAsync(ST, 0, (size_t)(6144 + 16) * sizeof(float), stream);
    gemm_tn<0,0><<<(N_ATOM+BM-1)/BM, 256, 0, stream>>>(atom_fea, OFEA, N_ATOM,
                                                       emb_W, OFEA, OFEA, AF, emb_b, X, AF);
    e_init<<<(NM*LDE+255)/256, 256, 0, stream>>>(nbr_fea, E48);

    for (int i = 0; i < NCONV; i++){
        mega_k<<<NBLK, TPB, DYN_LDS, stream>>>(
            X, E48, Hbuf, nbr_idx,
            WALL + (size_t)i*512*LDA_T, BIAS + i*512,
            ST + i*2048, BAR,
            bn1_g + i*O1, bn1_b + i*O1,
            bne_g + i*OE, bne_b + i*OE,
            bn3_g + i*O1, bn3_b + i*O1,
            bn2_g + i*AF, bn2_b + i*AF);
    }

    // head: Z = softplus(softplus(X) @ fc1W^T + fc1b); pooled mean; out
    gemm_tn<1,1><<<(N_ATOM+BM-1)/BM, 256, 0, stream>>>(X, AF, N_ATOM, fc1W, AF, AF, HID,
                                                       fc1b, Z, HID);
    pool_out_k<<<NCRY, 128, 0, stream>>>(Z, site_seg, outW, outb, (float*)d_out);
}

// Round 4
// 491.033 us; speedup vs baseline: 2.1268x; 1.0278x over previous
//
#include <hip/hip_runtime.h>
#include <hip/hip_bf16.h>

// Problem constants
#define N_ATOM 2000
#define MNBR   12
#define OFEA   92
#define AF     64
#define BFEA   41
#define K1     169   // 2A+B
#define O1     128
#define OE     82
#define NM     24000
#define NCONV  3
#define HID    128
#define NCRY   64
#define EPS_BN 1e-5f

#define LDA_T  192   // bf16 weight leading dim (169 padded to 192)
#define LDH    512   // REST: [h(0..127)|he(128..209)|pad|P'(256..383)|Q'(384..511)]
#define LDSW   88    // LDS row pitch (ushorts) for MFMA tiles
#define LDE    48    // padded E stride (41 -> 48, float4-aligned rows)

typedef __bf16 bf16x8 __attribute__((ext_vector_type(8)));
typedef float  f32x4  __attribute__((ext_vector_type(4)));

__device__ __forceinline__ float sigmoidf_(float x){
    return __builtin_amdgcn_rcpf(1.f + __expf(-x));
}
__device__ __forceinline__ float softplusf_(float x){
    return fmaxf(x,0.f) + __logf(1.f + __expf(-fabsf(x)));
}
__device__ __forceinline__ uint4 pack_bf16_8(const float* v){
    __hip_bfloat16 o[8];
    #pragma unroll
    for (int j=0;j<8;j++) o[j] = __float2bfloat16(v[j]);
    return *(const uint4*)o;
}

// ================= bf16 MFMA GEMM with fused gather (A-tile from X/E48/idx)
// and fused BN statistics in the epilogue.
// STL layout (floats): S1A[0..255] S2A[256..511] S13[512..639] S23[640..767]
//                      S12[768..831] S22[832..895] S2P[896..1023] S2Q[1024..1151]
__global__ __launch_bounds__(256, 3)
void gemm_fused(const float* __restrict__ X,
                const float* __restrict__ E48,
                const int*   __restrict__ idx,
                const __hip_bfloat16* __restrict__ W,
                const float* __restrict__ bias,
                float* __restrict__ REST,
                float* __restrict__ STL,
                float* __restrict__ SPA,
                float* __restrict__ SQA)
{
    __shared__ unsigned short As[128][LDSW];
    __shared__ unsigned short Ws[128][LDSW];
    __shared__ float cs1[128];
    __shared__ float cs2[128];
    __shared__ float spa[12][128];   // per-atom P'/Q' row-sums (block spans <=12 atoms)

    const int tid  = threadIdx.x;
    const int row0 = blockIdx.x * 128;
    const int col0 = blockIdx.y * 128;
    const int w    = tid >> 6;
    const int l    = tid & 63;
    const int wm   = w >> 1, wn = w & 1;
    const int lrow = l & 15;
    const int quad = l >> 4;

    if (tid < 128){ cs1[tid] = 0.f; cs2[tid] = 0.f; }
    for (int ii = tid; ii < 12*128; ii += 256) spa[ii>>7][ii&127] = 0.f;

    f32x4 acc[4][4];
    #pragma unroll
    for (int i=0;i<4;i++)
        #pragma unroll
        for (int j=0;j<4;j++) acc[i][j] = (f32x4){0.f,0.f,0.f,0.f};

    #pragma unroll
    for (int it = 0; it < 3; ++it){
        const int k0 = it * 64;
        if (it) __syncthreads();
        #pragma unroll
        for (int j = 0; j < 4; ++j){
            int e  = tid + j*256;
            int r  = e >> 3;
            int kk = (e & 7) << 3;
            int grow = row0 + r;
            float v[8];
            #pragma unroll
            for (int q2=0;q2<8;q2++) v[q2] = 0.f;
            if (grow < NM){
                if (it == 2){
                    if (kk < LDE){
                        const float* s = E48 + (size_t)grow*LDE + kk;
                        float4 a0 = *(const float4*)s;
                        float4 a1 = *(const float4*)(s+4);
                        v[0]=a0.x; v[1]=a0.y; v[2]=a0.z; v[3]=a0.w;
                        v[4]=a1.x; v[5]=a1.y; v[6]=a1.z; v[7]=a1.w;
                    }
                } else {
                    const float* s = (it == 0)
                        ? X + (size_t)((unsigned)grow/12u)*AF + kk
                        : X + (size_t)idx[grow]*AF + kk;
                    float4 a0 = *(const float4*)s;
                    float4 a1 = *(const float4*)(s+4);
                    v[0]=a0.x; v[1]=a0.y; v[2]=a0.z; v[3]=a0.w;
                    v[4]=a1.x; v[5]=a1.y; v[6]=a1.z; v[7]=a1.w;
                }
            }
            *(uint4*)(&As[r][kk]) = pack_bf16_8(v);
            uint4 vw = *(const uint4*)(W + (size_t)(col0 + r)*LDA_T + k0 + kk);
            *(uint4*)(&Ws[r][kk]) = vw;
        }
        __syncthreads();
        #pragma unroll
        for (int ks = 0; ks < 2; ++ks){
            int koff = ks*32 + quad*8;
            bf16x8 a_[4], b_[4];
            #pragma unroll
            for (int mi=0;mi<4;mi++)
                a_[mi] = *(const bf16x8*)(&As[wm*64 + mi*16 + lrow][koff]);
            #pragma unroll
            for (int ni=0;ni<4;ni++)
                b_[ni] = *(const bf16x8*)(&Ws[wn*64 + ni*16 + lrow][koff]);
            #pragma unroll
            for (int mi=0;mi<4;mi++)
                #pragma unroll
                for (int ni=0;ni<4;ni++)
                    acc[mi][ni] = __builtin_amdgcn_mfma_f32_16x16x32_bf16(
                        a_[mi], b_[ni], acc[mi][ni], 0, 0, 0);
        }
    }

    // ---------------- epilogue: store + fused BN stats ----------------
    const bool isPQ = (col0 >= 256);
    const int atomBase = (unsigned)row0 / 12u;
    int rbase_[4], n0_[4], sp_[4];
    #pragma unroll
    for (int mi=0;mi<4;mi++){
        rbase_[mi] = row0 + wm*64 + mi*16 + quad*4;
        int n0 = (int)((unsigned)rbase_[mi] / 12u);
        n0_[mi] = n0;
        sp_[mi] = 12 - (rbase_[mi] - n0*12);
    }

    #pragma unroll
    for (int ni=0;ni<4;ni++){
        const int cl  = wn*64 + ni*16 + lrow;   // 0..127 within block
        const int col = col0 + cl;
        const float bv = bias[col];
        float s1 = 0.f, s2 = 0.f;
        #pragma unroll
        for (int mi=0;mi<4;mi++){
            const int rbase = rbase_[mi];
            float run0 = 0.f, run1 = 0.f;
            #pragma unroll
            for (int reg=0;reg<4;reg++){
                int grow = rbase + reg;
                if (grow < NM){
                    float vv = acc[mi][ni][reg] + bv;
                    if (col0 != 128 || col < 210)     // cols 210..255 dead
                        REST[(size_t)grow*LDH + col] = vv;
                    s1 += vv; s2 += vv*vv;
                    if (isPQ){
                        if (reg < sp_[mi]) run0 += vv; else run1 += vv;
                    }
                }
            }
            if (isPQ){
                if (run0 != 0.f) atomicAdd(&spa[n0_[mi]     - atomBase][cl], run0);
                if (run1 != 0.f) atomicAdd(&spa[n0_[mi] + 1 - atomBase][cl], run1);
            }
        }
        if (isPQ){
            atomicAdd(&cs2[cl], s2);
        } else {
            atomicAdd(&cs1[cl], s1);
            atomicAdd(&cs2[cl], s2);
        }
    }
    __syncthreads();
    if (!isPQ){
        if (tid < 128){
            atomicAdd(&STL[col0 + tid],       cs1[tid]);   // S1A
            atomicAdd(&STL[256 + col0 + tid], cs2[tid]);   // S2A
        }
    } else {
        if (tid < 128)
            atomicAdd(&STL[(col0 == 256 ? 896 : 1024) + tid], cs2[tid]); // S2P / S2Q
        float* SPQd = (col0 == 256) ? SPA : SQA;
        for (int ii = tid; ii < 12*128; ii += 256){
            int ai = ii >> 7, c2 = ii & 127;
            int na = atomBase + ai;
            float val = spa[ai][c2];
            if (val != 0.f && na < N_ATOM)
                atomicAdd(&SPQd[(size_t)na*128 + c2], val);
        }
    }
}

// ================= fold per-atom P/Q sums into closed-form BN3 sums
__global__ __launch_bounds__(256)
void bn3_pre(const float* __restrict__ SPA, const float* __restrict__ SQA,
             float* __restrict__ STL)
{
    const int c    = threadIdx.x & 127;
    const int half = threadIdx.x >> 7;
    float s1 = 0.f, sx = 0.f;
    for (int n = blockIdx.x*2 + half; n < N_ATOM; n += 64){
        float p = SPA[(size_t)n*128 + c];
        float q = SQA[(size_t)n*128 + c];
        s1 += p + q;
        sx += p * q;
    }
    atomicAdd(&STL[512 + c], 12.f*s1);   // S13
    atomicAdd(&STL[640 + c], 2.f*sx);    // S23 cross term
}

// ================= small fp32 GEMM (embedding / head)
#define BM 64
#define BN 128
#define BK 32
template<int EPI, int SPIN>
__global__ __launch_bounds__(256)
void gemm_tn(const float* __restrict__ T, int ldt, int R,
             const float* __restrict__ W, int ldw, int K, int O,
             const float* __restrict__ bias,
             float* __restrict__ C, int ldc)
{
    __shared__ float Ts[BM][BK+1];
    __shared__ float Ws2[BN][BK+1];
    const int tid = threadIdx.x;
    const int row0 = blockIdx.x * BM;
    const int tx = tid % 16;
    const int ty = tid / 16;
    float acc[4][8];
    #pragma unroll
    for (int i=0;i<4;i++)
        #pragma unroll
        for (int j=0;j<8;j++) acc[i][j]=0.f;

    for (int k0 = 0; k0 < K; k0 += BK) {
        #pragma unroll
        for (int i=0;i<(BM*BK)/256;i++){
            int e = tid + i*256;
            int r = e / BK, k = e % BK;
            int gr = row0 + r, gk = k0 + k;
            float v = 0.f;
            if (gr < R && gk < K){
                v = T[(size_t)gr*ldt + gk];
                if (SPIN) v = softplusf_(v);
            }
            Ts[r][k] = v;
        }
        #pragma unroll
        for (int i=0;i<(BN*BK)/256;i++){
            int e = tid + i*256;
            int r = e / BK, k = e % BK;
            int gk = k0 + k;
            Ws2[r][k] = (r < O && gk < K) ? W[(size_t)r*ldw + gk] : 0.f;
        }
        __syncthreads();
        #pragma unroll
        for (int k=0;k<BK;k++){
            float a_[4], b_[8];
            #pragma unroll
            for (int i=0;i<4;i++) a_[i] = Ts[ty*4+i][k];
            #pragma unroll
            for (int j=0;j<8;j++) b_[j] = Ws2[tx + j*16][k];
            #pragma unroll
            for (int i=0;i<4;i++)
                #pragma unroll
                for (int j=0;j<8;j++)
                    acc[i][j] += a_[i]*b_[j];
        }
        __syncthreads();
    }
    #pragma unroll
    for (int i=0;i<4;i++){
        int gr = row0 + ty*4 + i;
        if (gr >= R) continue;
        #pragma unroll
        for (int j=0;j<8;j++){
            int gc = tx + j*16;
            if (gc >= O) continue;
            float v = acc[i][j] + (bias ? bias[gc] : 0.f);
            if (EPI==1) v = softplusf_(v);
            C[(size_t)gr*ldc + gc] = v;
        }
    }
}

// ================= pack weights (bf16) + bias (fp32).
__global__ void pack_all(const float* __restrict__ fcW, const float* __restrict__ eW,
                         const float* __restrict__ W3, const float* __restrict__ fcb,
                         const float* __restrict__ eb, const float* __restrict__ b3,
                         __hip_bfloat16* __restrict__ WALL, float* __restrict__ BIAS)
{
    int i = blockIdx.x*blockDim.x + threadIdx.x;
    const int nW = NCONV*512*LDA_T;
    if (i < nW){
        int ll = i/(512*LDA_T), rem = i%(512*LDA_T);
        int c = rem/LDA_T, k = rem%LDA_T;
        float v = 0.f;
        if (c < O1){
            if (k < K1) v = fcW[((size_t)ll*O1 + c)*K1 + k];
        } else if (c < O1+OE){
            if (k < K1) v = eW[((size_t)ll*OE + (c-O1))*K1 + k];
        } else if (c >= 256 && c < 384){
            int o = c - 256;
            const float* W3l = W3 + (size_t)ll*O1*274;
            if (k < AF)                        v = 0.5f * W3l[(size_t)o*274 + k];          // Wa/2
            else if (k < 2*AF)                 v = W3l[(size_t)o*274 + k];                 // Wj
            else if (k < K1)                   v = W3l[(size_t)o*274 + 192 + (k-128)];     // Wij
        } else if (c >= 384){
            int o = c - 384;
            const float* W3l = W3 + (size_t)ll*O1*274;
            if (k < AF)                        v = 0.5f * W3l[(size_t)o*274 + k];          // Wa/2
            else if (k < 2*AF)                 v = W3l[(size_t)o*274 + k + AF];            // Wl
            else if (k < K1)                   v = W3l[(size_t)o*274 + 233 + (k-128)];     // Wil
        }
        WALL[i] = __float2bfloat16(v);
    } else if (i < nW + NCONV*512){
        int m = i - nW;
        int ll = m/512, c = m%512;
        float v = 0.f;
        if (c < O1)         v = fcb[ll*O1 + c];
        else if (c < O1+OE) v = eb[ll*OE + (c-O1)];
        else if (c >= 256)  v = 0.5f * b3[ll*O1 + ((c-256)&127)];
        BIAS[m] = v;
    }
}

// ================= nbr_fea [NM][41] -> E48 [NM][48] (zero-padded)
__global__ void e_init(const float* __restrict__ nbr, float* __restrict__ E48)
{
    int i = blockIdx.x*blockDim.x + threadIdx.x;
    if (i >= NM*LDE) return;
    int r = i / LDE, k = i % LDE;
    E48[i] = (k < BFEA) ? nbr[(size_t)r*BFEA + k] : 0.f;
}

// ================= consumer: block = atom, 128 threads.
// Inlined BN finalize (from STL) + 2/3-body + edge update + fused TB stats.
__global__ __launch_bounds__(128)
void consumer_k(const float* __restrict__ REST, float* __restrict__ STL,
                float* __restrict__ TB, float* __restrict__ E48,
                const float* __restrict__ g1, const float* __restrict__ b1,
                const float* __restrict__ ge, const float* __restrict__ be,
                const float* __restrict__ g3, const float* __restrict__ b3b)
{
    __shared__ float red[128];
    __shared__ float scA[210], shA[210], sc3v[128], sh3v[128];
    const int n = blockIdx.x;
    const int t = threadIdx.x;
    const int a = t & 63;
    const int g = t >> 6;     // 0..1

    // ---- BN finalize (redundant per block; trivial ALU) ----
    for (int c = t; c < 210; c += 128){
        float mean = STL[c]*(1.f/NM);
        float var  = fmaxf(STL[256+c]*(1.f/NM) - mean*mean, 0.f);
        float gg = (c < O1) ? g1[c] : ge[c-O1];
        float bb = (c < O1) ? b1[c] : be[c-O1];
        float sc = gg * rsqrtf(var + EPS_BN);
        scA[c] = sc; shA[c] = bb - sc*mean;
    }
    {
        int c = t;
        if (c < 128){
            float inv  = 1.f/((float)NM*MNBR);
            float mean = STL[512+c]*inv;
            float ex2  = (STL[640+c] + 12.f*(STL[896+c] + STL[1024+c]))*inv;
            float var  = fmaxf(ex2 - mean*mean, 0.f);
            float sc = g3[c] * rsqrtf(var + EPS_BN);
            sc3v[c] = sc; sh3v[c] = b3b[c] - sc*mean;
        }
    }
    __syncthreads();

    const float* base = REST + (size_t)n*MNBR*LDH;
    float sha = scA[a],     tha = shA[a];
    float shb = scA[64+a],  thb = shA[64+a];
    float s3lo = sc3v[a],   s3hi = sc3v[64+a];
    float t3lo = sh3v[a],   t3hi = sh3v[64+a];

    float Qa[MNBR], Qb[MNBR];
    #pragma unroll
    for (int m=0;m<MNBR;m++){
        const float* row = base + (size_t)m*LDH;
        Qa[m] = s3lo*row[384+a];
        Qb[m] = s3hi*row[448+a];
    }
    float acc = 0.f;
    #pragma unroll
    for (int j=0;j<6;j++){
        const float* row = base + (size_t)(g*6+j)*LDH;
        acc += sigmoidf_(sha*row[a]+tha) * softplusf_(shb*row[64+a]+thb);
        float ua = s3lo*row[256+a] + t3lo;
        float ub = s3hi*row[320+a] + t3hi;
        #pragma unroll
        for (int l2=0;l2<MNBR;l2++)
            acc += sigmoidf_(ua + Qa[l2]) * softplusf_(ub + Qb[l2]);
    }
    red[t] = acc;
    __syncthreads();
    if (g == 0){
        float v = red[a] + red[64+a];
        TB[(size_t)n*AF + a] = v;
        atomicAdd(&STL[768+a], v);       // S12
        atomicAdd(&STL[832+a], v*v);     // S22
    }
    // edge update on padded E48
    for (int idx = t; idx < MNBR*BFEA; idx += 128){
        int m = idx / BFEA, b = idx % BFEA;
        const float* row = base + (size_t)m*LDH;
        float u = scA[O1+b]*row[O1+b]   + shA[O1+b];
        float v = scA[169+b]*row[169+b] + shA[169+b];
        E48[((size_t)n*MNBR + m)*LDE + b] += sigmoidf_(u) * softplusf_(v);
    }
}

// ================= x = softplus(x + bn2(TB)), inline finalize
__global__ void x_update_k(float* __restrict__ X, const float* __restrict__ TB,
                           const float* __restrict__ S12, const float* __restrict__ S22,
                           const float* __restrict__ g2, const float* __restrict__ b2,
                           int total)
{
    int i = blockIdx.x*blockDim.x + threadIdx.x;
    if (i >= total) return;
    int a = i & (AF-1);
    float mean = S12[a]*(1.f/N_ATOM);
    float var  = fmaxf(S22[a]*(1.f/N_ATOM) - mean*mean, 0.f);
    float sc = g2[a]*rsqrtf(var + EPS_BN);
    X[i] = softplusf_(X[i] + sc*TB[i] + (b2[a] - sc*mean));
}

// ================= pooled mean per crystal + final dot
__global__ __launch_bounds__(128)
void pool_out_k(const float* __restrict__ Z, const int* __restrict__ seg,
                const float* __restrict__ outW, const float* __restrict__ outb,
                float* __restrict__ out)
{
    __shared__ float red[128];
    const int c = blockIdx.x;
    const int h = threadIdx.x;
    int l0, l1;
    {
        int l=0, r=N_ATOM;
        while (l<r){ int m=(l+r)>>1; if (seg[m] < c) l=m+1; else r=m; }
        l0 = l;
        l=l0; r=N_ATOM;
        while (l<r){ int m=(l+r)>>1; if (seg[m] < c+1) l=m+1; else r=m; }
        l1 = l;
    }
    float s = 0.f;
    for (int n = l0; n < l1; ++n) s += Z[(size_t)n*HID + h];
    float cnt = fmaxf((float)(l1-l0), 1.f);
    red[h] = (s/cnt) * outW[h];
    __syncthreads();
    for (int off=64; off>0; off>>=1){
        if (h < off) red[h] += red[h+off];
        __syncthreads();
    }
    if (h == 0) out[c] = red[0] + outb[0];
}

extern "C" void kernel_launch(void* const* d_in, const int* in_sizes, int n_in,
                              void* d_out, int out_size, void* d_ws, size_t ws_size,
                              hipStream_t stream)
{
    const float* atom_fea = (const float*)d_in[0];
    const float* nbr_fea  = (const float*)d_in[1];
    const int*   nbr_idx  = (const int*)d_in[2];
    const int*   site_seg = (const int*)d_in[3];
    const float* emb_W = (const float*)d_in[4];
    const float* emb_b = (const float*)d_in[5];
    const float* fcW   = (const float*)d_in[6];
    const float* fcb   = (const float*)d_in[7];
    const float* bn1_g = (const float*)d_in[8];
    const float* bn1_b = (const float*)d_in[9];
    const float* bn2_g = (const float*)d_in[10];
    const float* bn2_b = (const float*)d_in[11];
    const float* eW    = (const float*)d_in[12];
    const float* eb    = (const float*)d_in[13];
    const float* bne_g = (const float*)d_in[14];
    const float* bne_b = (const float*)d_in[15];
    const float* W3    = (const float*)d_in[16];
    const float* b3    = (const float*)d_in[17];
    const float* bn3_g = (const float*)d_in[18];
    const float* bn3_b = (const float*)d_in[19];
    const float* fc1W  = (const float*)d_in[20];
    const float* fc1b  = (const float*)d_in[21];
    const float* outW  = (const float*)d_in[22];
    const float* outb  = (const float*)d_in[23];

    // workspace layout (float units) — same map as R1
    float* ws   = (float*)d_ws;
    float* X    = ws;                          // 128,000
    float* E48  = ws + 128000;                 // 1,152,000 -> 1,280,000
    float* REST = ws + 1280000;                // 24000*512 = 12,288,000
    float* TB   = ws + 13568000;               // 128,000
    float* Z    = ws + 13696000;               // 256,000
    float* ST   = ws + 13952000;               // 3*2048 = 6,144
    float* SCu  = ws + 13958144;               // 1,024 (unused, keeps offsets)
    float* SPQ  = ws + 13959168;               // 3 * 2 * 256,000 = 1,536,000
    __hip_bfloat16* WALL = (__hip_bfloat16*)(ws + 15495168); // 3*512*192 bf16
    float* BIAS = ws + 15642624;               // 1,536
    (void)SCu;

    {
        int tot = NCONV*512*LDA_T + NCONV*512;
        pack_all<<<(tot+255)/256, 256, 0, stream>>>(fcW, eW, W3, fcb, eb, b3, WALL, BIAS);
    }
    // zero ST + SC + all per-layer SPA/SQA in one contiguous fill
    hipMemsetAsync(ST, 0, (size_t)(6144 + 1024 + 1536000) * sizeof(float), stream);
    gemm_tn<0,0><<<(N_ATOM+BM-1)/BM, 256, 0, stream>>>(atom_fea, OFEA, N_ATOM,
                                                       emb_W, OFEA, OFEA, AF, emb_b, X, AF);
    e_init<<<(NM*LDE+255)/256, 256, 0, stream>>>(nbr_fea, E48);

    for (int i = 0; i < NCONV; i++){
        float* STL = ST + i*2048;
        float* SPA = SPQ + (size_t)i*512000;
        float* SQA = SPA + 256000;

        {
            dim3 g((NM+127)/128, 4);
            gemm_fused<<<g, 256, 0, stream>>>(X, E48, nbr_idx,
                                              WALL + (size_t)i*512*LDA_T,
                                              BIAS + i*512, REST, STL, SPA, SQA);
        }
        bn3_pre<<<32, 256, 0, stream>>>(SPA, SQA, STL);
        consumer_k<<<N_ATOM, 128, 0, stream>>>(REST, STL, TB, E48,
                                               bn1_g + i*O1, bn1_b + i*O1,
                                               bne_g + i*OE, bne_b + i*OE,
                                               bn3_g + i*O1, bn3_b + i*O1);
        x_update_k<<<(N_ATOM*AF+255)/256, 256, 0, stream>>>(X, TB, STL+768, STL+832,
                                                            bn2_g + i*AF, bn2_b + i*AF,
                                                            N_ATOM*AF);
    }

    // head: Z = softplus(softplus(X) @ fc1W^T + fc1b); pooled mean; out
    gemm_tn<1,1><<<(N_ATOM+BM-1)/BM, 256, 0, stream>>>(X, AF, N_ATOM, fc1W, AF, AF, HID,
                                                       fc1b, Z, HID);
    pool_out_k<<<NCRY, 128, 0, stream>>>(Z, site_seg, outW, outb, (float*)d_out);
}

// Round 5
// 389.979 us; speedup vs baseline: 2.6779x; 1.2591x over previous
//
#include <hip/hip_runtime.h>
#include <hip/hip_bf16.h>

// Problem constants
#define N_ATOM 2000
#define MNBR   12
#define OFEA   92
#define AF     64
#define BFEA   41
#define K1     169   // 2A+B
#define O1     128
#define OE     82
#define NM     24000
#define NCONV  3
#define HID    128
#define NCRY   64
#define EPS_BN 1e-5f

#define LDA_T  192   // bf16 weight leading dim (169 padded to 192)
#define LDH    512   // REST: [h(0..127)|he(128..209)|pad|P'(256..383)|Q'(384..511)]
#define LDSW   88    // LDS row pitch (ushorts) for MFMA tiles
#define LDE    48    // padded E stride (41 -> 48, float4-aligned rows)

typedef __bf16 bf16x8 __attribute__((ext_vector_type(8)));
typedef float  f32x4  __attribute__((ext_vector_type(4)));

__device__ __forceinline__ float sigmoidf_(float x){
    return __builtin_amdgcn_rcpf(1.f + __expf(-x));
}
__device__ __forceinline__ float softplusf_(float x){
    return fmaxf(x,0.f) + __logf(1.f + __expf(-fabsf(x)));
}
__device__ __forceinline__ uint4 pack_bf16_8(const float* v){
    __hip_bfloat16 o[8];
    #pragma unroll
    for (int j=0;j<8;j++) o[j] = __float2bfloat16(v[j]);
    return *(const uint4*)o;
}

// ================= bf16 MFMA GEMM with fused gather (A-tile from X/E48/idx)
// and fused BN statistics in the epilogue.
// STL layout (floats): S1A[0..255] S2A[256..511] S13[512..639] S23[640..767]
//                      S12[768..831] S22[832..895] S2P[896..1023] S2Q[1024..1151]
__global__ __launch_bounds__(256, 3)
void gemm_fused(const float* __restrict__ X,
                const float* __restrict__ E48,
                const int*   __restrict__ idx,
                const __hip_bfloat16* __restrict__ W,
                const float* __restrict__ bias,
                float* __restrict__ REST,
                float* __restrict__ STL,
                float* __restrict__ SPA,
                float* __restrict__ SQA)
{
    __shared__ unsigned short As[128][LDSW];
    __shared__ unsigned short Ws[128][LDSW];
    __shared__ float cs1[128];
    __shared__ float cs2[128];
    __shared__ float spa[12][128];   // per-atom P'/Q' row-sums (block spans <=12 atoms)

    const int tid  = threadIdx.x;
    const int row0 = blockIdx.x * 128;
    const int col0 = blockIdx.y * 128;
    const int w    = tid >> 6;
    const int l    = tid & 63;
    const int wm   = w >> 1, wn = w & 1;
    const int lrow = l & 15;
    const int quad = l >> 4;

    if (tid < 128){ cs1[tid] = 0.f; cs2[tid] = 0.f; }
    for (int ii = tid; ii < 12*128; ii += 256) spa[ii>>7][ii&127] = 0.f;

    f32x4 acc[4][4];
    #pragma unroll
    for (int i=0;i<4;i++)
        #pragma unroll
        for (int j=0;j<4;j++) acc[i][j] = (f32x4){0.f,0.f,0.f,0.f};

    #pragma unroll
    for (int it = 0; it < 3; ++it){
        const int k0 = it * 64;
        if (it) __syncthreads();
        #pragma unroll
        for (int j = 0; j < 4; ++j){
            int e  = tid + j*256;
            int r  = e >> 3;
            int kk = (e & 7) << 3;
            int grow = row0 + r;
            float v[8];
            #pragma unroll
            for (int q2=0;q2<8;q2++) v[q2] = 0.f;
            if (grow < NM){
                if (it == 2){
                    if (kk < LDE){
                        const float* s = E48 + (size_t)grow*LDE + kk;
                        float4 a0 = *(const float4*)s;
                        float4 a1 = *(const float4*)(s+4);
                        v[0]=a0.x; v[1]=a0.y; v[2]=a0.z; v[3]=a0.w;
                        v[4]=a1.x; v[5]=a1.y; v[6]=a1.z; v[7]=a1.w;
                    }
                } else {
                    const float* s = (it == 0)
                        ? X + (size_t)((unsigned)grow/12u)*AF + kk
                        : X + (size_t)idx[grow]*AF + kk;
                    float4 a0 = *(const float4*)s;
                    float4 a1 = *(const float4*)(s+4);
                    v[0]=a0.x; v[1]=a0.y; v[2]=a0.z; v[3]=a0.w;
                    v[4]=a1.x; v[5]=a1.y; v[6]=a1.z; v[7]=a1.w;
                }
            }
            *(uint4*)(&As[r][kk]) = pack_bf16_8(v);
            uint4 vw = *(const uint4*)(W + (size_t)(col0 + r)*LDA_T + k0 + kk);
            *(uint4*)(&Ws[r][kk]) = vw;
        }
        __syncthreads();
        #pragma unroll
        for (int ks = 0; ks < 2; ++ks){
            int koff = ks*32 + quad*8;
            bf16x8 a_[4], b_[4];
            #pragma unroll
            for (int mi=0;mi<4;mi++)
                a_[mi] = *(const bf16x8*)(&As[wm*64 + mi*16 + lrow][koff]);
            #pragma unroll
            for (int ni=0;ni<4;ni++)
                b_[ni] = *(const bf16x8*)(&Ws[wn*64 + ni*16 + lrow][koff]);
            #pragma unroll
            for (int mi=0;mi<4;mi++)
                #pragma unroll
                for (int ni=0;ni<4;ni++)
                    acc[mi][ni] = __builtin_amdgcn_mfma_f32_16x16x32_bf16(
                        a_[mi], b_[ni], acc[mi][ni], 0, 0, 0);
        }
    }

    // ---------------- epilogue: store + fused BN stats ----------------
    const bool isPQ = (col0 >= 256);
    const int atomBase = (unsigned)row0 / 12u;
    int rbase_[4], n0_[4], sp_[4];
    #pragma unroll
    for (int mi=0;mi<4;mi++){
        rbase_[mi] = row0 + wm*64 + mi*16 + quad*4;
        int n0 = (int)((unsigned)rbase_[mi] / 12u);
        n0_[mi] = n0;
        sp_[mi] = 12 - (rbase_[mi] - n0*12);
    }

    #pragma unroll
    for (int ni=0;ni<4;ni++){
        const int cl  = wn*64 + ni*16 + lrow;   // 0..127 within block
        const int col = col0 + cl;
        const float bv = bias[col];
        float s1 = 0.f, s2 = 0.f;
        #pragma unroll
        for (int mi=0;mi<4;mi++){
            const int rbase = rbase_[mi];
            float run0 = 0.f, run1 = 0.f;
            #pragma unroll
            for (int reg=0;reg<4;reg++){
                int grow = rbase + reg;
                if (grow < NM){
                    float vv = acc[mi][ni][reg] + bv;
                    if (col0 != 128 || col < 210)     // cols 210..255 dead
                        REST[(size_t)grow*LDH + col] = vv;
                    s1 += vv; s2 += vv*vv;
                    if (isPQ){
                        if (reg < sp_[mi]) run0 += vv; else run1 += vv;
                    }
                }
            }
            if (isPQ){
                if (run0 != 0.f) atomicAdd(&spa[n0_[mi]     - atomBase][cl], run0);
                if (run1 != 0.f) atomicAdd(&spa[n0_[mi] + 1 - atomBase][cl], run1);
            }
        }
        if (isPQ){
            atomicAdd(&cs2[cl], s2);
        } else {
            atomicAdd(&cs1[cl], s1);
            atomicAdd(&cs2[cl], s2);
        }
    }
    __syncthreads();
    if (!isPQ){
        if (tid < 128){
            atomicAdd(&STL[col0 + tid],       cs1[tid]);   // S1A
            atomicAdd(&STL[256 + col0 + tid], cs2[tid]);   // S2A
        }
    } else {
        if (tid < 128)
            atomicAdd(&STL[(col0 == 256 ? 896 : 1024) + tid], cs2[tid]); // S2P / S2Q
        float* SPQd = (col0 == 256) ? SPA : SQA;
        for (int ii = tid; ii < 12*128; ii += 256){
            int ai = ii >> 7, c2 = ii & 127;
            int na = atomBase + ai;
            float val = spa[ai][c2];
            if (val != 0.f && na < N_ATOM)
                atomicAdd(&SPQd[(size_t)na*128 + c2], val);
        }
    }
}

// ================= fold per-atom P/Q sums into closed-form BN3 sums
__global__ __launch_bounds__(256)
void bn3_pre(const float* __restrict__ SPA, const float* __restrict__ SQA,
             float* __restrict__ STL)
{
    const int c    = threadIdx.x & 127;
    const int half = threadIdx.x >> 7;
    float s1 = 0.f, sx = 0.f;
    for (int n = blockIdx.x*2 + half; n < N_ATOM; n += 64){
        float p = SPA[(size_t)n*128 + c];
        float q = SQA[(size_t)n*128 + c];
        s1 += p + q;
        sx += p * q;
    }
    atomicAdd(&STL[512 + c], 12.f*s1);   // S13
    atomicAdd(&STL[640 + c], 2.f*sx);    // S23 cross term
}

// ================= small fp32 GEMM (embedding / head)
#define BM 64
#define BN 128
#define BK 32
template<int EPI, int SPIN>
__global__ __launch_bounds__(256)
void gemm_tn(const float* __restrict__ T, int ldt, int R,
             const float* __restrict__ W, int ldw, int K, int O,
             const float* __restrict__ bias,
             float* __restrict__ C, int ldc)
{
    __shared__ float Ts[BM][BK+1];
    __shared__ float Ws2[BN][BK+1];
    const int tid = threadIdx.x;
    const int row0 = blockIdx.x * BM;
    const int tx = tid % 16;
    const int ty = tid / 16;
    float acc[4][8];
    #pragma unroll
    for (int i=0;i<4;i++)
        #pragma unroll
        for (int j=0;j<8;j++) acc[i][j]=0.f;

    for (int k0 = 0; k0 < K; k0 += BK) {
        #pragma unroll
        for (int i=0;i<(BM*BK)/256;i++){
            int e = tid + i*256;
            int r = e / BK, k = e % BK;
            int gr = row0 + r, gk = k0 + k;
            float v = 0.f;
            if (gr < R && gk < K){
                v = T[(size_t)gr*ldt + gk];
                if (SPIN) v = softplusf_(v);
            }
            Ts[r][k] = v;
        }
        #pragma unroll
        for (int i=0;i<(BN*BK)/256;i++){
            int e = tid + i*256;
            int r = e / BK, k = e % BK;
            int gk = k0 + k;
            Ws2[r][k] = (r < O && gk < K) ? W[(size_t)r*ldw + gk] : 0.f;
        }
        __syncthreads();
        #pragma unroll
        for (int k=0;k<BK;k++){
            float a_[4], b_[8];
            #pragma unroll
            for (int i=0;i<4;i++) a_[i] = Ts[ty*4+i][k];
            #pragma unroll
            for (int j=0;j<8;j++) b_[j] = Ws2[tx + j*16][k];
            #pragma unroll
            for (int i=0;i<4;i++)
                #pragma unroll
                for (int j=0;j<8;j++)
                    acc[i][j] += a_[i]*b_[j];
        }
        __syncthreads();
    }
    #pragma unroll
    for (int i=0;i<4;i++){
        int gr = row0 + ty*4 + i;
        if (gr >= R) continue;
        #pragma unroll
        for (int j=0;j<8;j++){
            int gc = tx + j*16;
            if (gc >= O) continue;
            float v = acc[i][j] + (bias ? bias[gc] : 0.f);
            if (EPI==1) v = softplusf_(v);
            C[(size_t)gr*ldc + gc] = v;
        }
    }
}

// ================= pack weights (bf16) + bias (fp32).
__global__ void pack_all(const float* __restrict__ fcW, const float* __restrict__ eW,
                         const float* __restrict__ W3, const float* __restrict__ fcb,
                         const float* __restrict__ eb, const float* __restrict__ b3,
                         __hip_bfloat16* __restrict__ WALL, float* __restrict__ BIAS)
{
    int i = blockIdx.x*blockDim.x + threadIdx.x;
    const int nW = NCONV*512*LDA_T;
    if (i < nW){
        int ll = i/(512*LDA_T), rem = i%(512*LDA_T);
        int c = rem/LDA_T, k = rem%LDA_T;
        float v = 0.f;
        if (c < O1){
            if (k < K1) v = fcW[((size_t)ll*O1 + c)*K1 + k];
        } else if (c < O1+OE){
            if (k < K1) v = eW[((size_t)ll*OE + (c-O1))*K1 + k];
        } else if (c >= 256 && c < 384){
            int o = c - 256;
            const float* W3l = W3 + (size_t)ll*O1*274;
            if (k < AF)                        v = 0.5f * W3l[(size_t)o*274 + k];          // Wa/2
            else if (k < 2*AF)                 v = W3l[(size_t)o*274 + k];                 // Wj
            else if (k < K1)                   v = W3l[(size_t)o*274 + 192 + (k-128)];     // Wij
        } else if (c >= 384){
            int o = c - 384;
            const float* W3l = W3 + (size_t)ll*O1*274;
            if (k < AF)                        v = 0.5f * W3l[(size_t)o*274 + k];          // Wa/2
            else if (k < 2*AF)                 v = W3l[(size_t)o*274 + k + AF];            // Wl
            else if (k < K1)                   v = W3l[(size_t)o*274 + 233 + (k-128)];     // Wil
        }
        WALL[i] = __float2bfloat16(v);
    } else if (i < nW + NCONV*512){
        int m = i - nW;
        int ll = m/512, c = m%512;
        float v = 0.f;
        if (c < O1)         v = fcb[ll*O1 + c];
        else if (c < O1+OE) v = eb[ll*OE + (c-O1)];
        else if (c >= 256)  v = 0.5f * b3[ll*O1 + ((c-256)&127)];
        BIAS[m] = v;
    }
}

// ================= nbr_fea [NM][41] -> E48 [NM][48] (zero-padded)
__global__ void e_init(const float* __restrict__ nbr, float* __restrict__ E48)
{
    int i = blockIdx.x*blockDim.x + threadIdx.x;
    if (i >= NM*LDE) return;
    int r = i / LDE, k = i % LDE;
    E48[i] = (k < BFEA) ? nbr[(size_t)r*BFEA + k] : 0.f;
}

// ================= consumer: block = atom, 256 threads (4 waves x 3 m's each).
// Inlined BN finalize; factored-exponential 3-body inner loop.
__global__ __launch_bounds__(256)
void consumer_k(const float* __restrict__ REST, const float* __restrict__ STL,
                float* __restrict__ TB, float* __restrict__ E48,
                const float* __restrict__ g1, const float* __restrict__ b1,
                const float* __restrict__ ge, const float* __restrict__ be,
                const float* __restrict__ g3, const float* __restrict__ b3b)
{
    __shared__ float red[256];
    __shared__ float scA[210], shA[210], sc3v[128], sh3v[128];
    const int n = blockIdx.x;
    const int t = threadIdx.x;
    const int a = t & 63;
    const int g = t >> 6;     // 0..3, each owns 3 m's

    // ---- BN finalize (redundant per block; trivial ALU) ----
    if (t < 210){
        float mean = STL[t]*(1.f/NM);
        float var  = fmaxf(STL[256+t]*(1.f/NM) - mean*mean, 0.f);
        float gg = (t < O1) ? g1[t] : ge[t-O1];
        float bb = (t < O1) ? b1[t] : be[t-O1];
        float sc = gg * rsqrtf(var + EPS_BN);
        scA[t] = sc; shA[t] = bb - sc*mean;
    }
    if (t < 128){
        float inv  = 1.f/((float)NM*MNBR);
        float mean = STL[512+t]*inv;
        float ex2  = (STL[640+t] + 12.f*(STL[896+t] + STL[1024+t]))*inv;
        float var  = fmaxf(ex2 - mean*mean, 0.f);
        float sc = g3[t] * rsqrtf(var + EPS_BN);
        sc3v[t] = sc; sh3v[t] = b3b[t] - sc*mean;
    }
    __syncthreads();

    const float* base = REST + (size_t)n*MNBR*LDH;
    const float s3lo = sc3v[a],  s3hi = sc3v[64+a];
    const float t3lo = sh3v[a],  t3hi = sh3v[64+a];

    // factored exponentials for all 12 l: e^{-Qa[l]}, e^{+Qb[l]}
    float Ea[MNBR], Fb[MNBR];
    #pragma unroll
    for (int m=0;m<MNBR;m++){
        const float* row = base + (size_t)m*LDH;
        Ea[m] = __expf(-(s3lo*row[384+a]));
        Fb[m] = __expf( (s3hi*row[448+a]));
    }
    const float sha = scA[a],    tha = shA[a];
    const float shb = scA[64+a], thb = shA[64+a];
    float acc = 0.f;
    #pragma unroll
    for (int j=0;j<3;j++){
        const float* row = base + (size_t)(g*3+j)*LDH;
        // 2-body term for this m
        acc += sigmoidf_(sha*row[a]+tha) * softplusf_(shb*row[64+a]+thb);
        // 3-body: sigma(ua+Qa[l]) * softplus(ub+Qb[l]) with factored exps
        float ua = s3lo*row[256+a] + t3lo;
        float ub = s3hi*row[320+a] + t3hi;
        float Em = __expf(-ua);
        float Fm = __expf(ub);
        #pragma unroll
        for (int l2=0;l2<MNBR;l2++){
            float s = __builtin_amdgcn_rcpf(1.f + Em*Ea[l2]);
            float p = __logf(1.f + Fm*Fb[l2]);
            acc += s*p;
        }
    }
    red[t] = acc;
    __syncthreads();
    if (t < 64)
        TB[(size_t)n*AF + t] = red[t] + red[64+t] + red[128+t] + red[192+t];
    // edge update on padded E48
    for (int idx = t; idx < MNBR*BFEA; idx += 256){
        int m = idx / BFEA, b = idx % BFEA;
        const float* row = base + (size_t)m*LDH;
        float u = scA[O1+b]*row[O1+b]   + shA[O1+b];
        float v = scA[169+b]*row[169+b] + shA[169+b];
        E48[((size_t)n*MNBR + m)*LDE + b] += sigmoidf_(u) * softplusf_(v);
    }
}

// ================= per-column sum/sumsq for TB (low-contention)
__global__ __launch_bounds__(64)
void tb_stats_k(const float* __restrict__ TB,
                float* __restrict__ S1, float* __restrict__ S2)
{
    int t = threadIdx.x;
    float s1 = 0.f, s2 = 0.f;
    for (int r = blockIdx.x; r < N_ATOM; r += gridDim.x){
        float v = TB[(size_t)r*AF + t];
        s1 += v; s2 += v*v;
    }
    atomicAdd(&S1[t], s1);
    atomicAdd(&S2[t], s2);
}

// ================= x = softplus(x + bn2(TB)), inline finalize
__global__ void x_update_k(float* __restrict__ X, const float* __restrict__ TB,
                           const float* __restrict__ S12, const float* __restrict__ S22,
                           const float* __restrict__ g2, const float* __restrict__ b2,
                           int total)
{
    int i = blockIdx.x*blockDim.x + threadIdx.x;
    if (i >= total) return;
    int a = i & (AF-1);
    float mean = S12[a]*(1.f/N_ATOM);
    float var  = fmaxf(S22[a]*(1.f/N_ATOM) - mean*mean, 0.f);
    float sc = g2[a]*rsqrtf(var + EPS_BN);
    X[i] = softplusf_(X[i] + sc*TB[i] + (b2[a] - sc*mean));
}

// ================= pooled mean per crystal + final dot
__global__ __launch_bounds__(128)
void pool_out_k(const float* __restrict__ Z, const int* __restrict__ seg,
                const float* __restrict__ outW, const float* __restrict__ outb,
                float* __restrict__ out)
{
    __shared__ float red[128];
    const int c = blockIdx.x;
    const int h = threadIdx.x;
    int l0, l1;
    {
        int l=0, r=N_ATOM;
        while (l<r){ int m=(l+r)>>1; if (seg[m] < c) l=m+1; else r=m; }
        l0 = l;
        l=l0; r=N_ATOM;
        while (l<r){ int m=(l+r)>>1; if (seg[m] < c+1) l=m+1; else r=m; }
        l1 = l;
    }
    float s = 0.f;
    for (int n = l0; n < l1; ++n) s += Z[(size_t)n*HID + h];
    float cnt = fmaxf((float)(l1-l0), 1.f);
    red[h] = (s/cnt) * outW[h];
    __syncthreads();
    for (int off=64; off>0; off>>=1){
        if (h < off) red[h] += red[h+off];
        __syncthreads();
    }
    if (h == 0) out[c] = red[0] + outb[0];
}

extern "C" void kernel_launch(void* const* d_in, const int* in_sizes, int n_in,
                              void* d_out, int out_size, void* d_ws, size_t ws_size,
                              hipStream_t stream)
{
    const float* atom_fea = (const float*)d_in[0];
    const float* nbr_fea  = (const float*)d_in[1];
    const int*   nbr_idx  = (const int*)d_in[2];
    const int*   site_seg = (const int*)d_in[3];
    const float* emb_W = (const float*)d_in[4];
    const float* emb_b = (const float*)d_in[5];
    const float* fcW   = (const float*)d_in[6];
    const float* fcb   = (const float*)d_in[7];
    const float* bn1_g = (const float*)d_in[8];
    const float* bn1_b = (const float*)d_in[9];
    const float* bn2_g = (const float*)d_in[10];
    const float* bn2_b = (const float*)d_in[11];
    const float* eW    = (const float*)d_in[12];
    const float* eb    = (const float*)d_in[13];
    const float* bne_g = (const float*)d_in[14];
    const float* bne_b = (const float*)d_in[15];
    const float* W3    = (const float*)d_in[16];
    const float* b3    = (const float*)d_in[17];
    const float* bn3_g = (const float*)d_in[18];
    const float* bn3_b = (const float*)d_in[19];
    const float* fc1W  = (const float*)d_in[20];
    const float* fc1b  = (const float*)d_in[21];
    const float* outW  = (const float*)d_in[22];
    const float* outb  = (const float*)d_in[23];

    // workspace layout (float units)
    float* ws   = (float*)d_ws;
    float* X    = ws;                          // 128,000
    float* E48  = ws + 128000;                 // 1,152,000 -> 1,280,000
    float* REST = ws + 1280000;                // 24000*512 = 12,288,000
    float* TB   = ws + 13568000;               // 128,000
    float* Z    = ws + 13696000;               // 256,000
    float* ST   = ws + 13952000;               // 3*2048 = 6,144
    float* SCu  = ws + 13958144;               // 1,024 (unused, keeps offsets)
    float* SPQ  = ws + 13959168;               // 3 * 2 * 256,000 = 1,536,000
    __hip_bfloat16* WALL = (__hip_bfloat16*)(ws + 15495168); // 3*512*192 bf16
    float* BIAS = ws + 15642624;               // 1,536
    (void)SCu;

    {
        int tot = NCONV*512*LDA_T + NCONV*512;
        pack_all<<<(tot+255)/256, 256, 0, stream>>>(fcW, eW, W3, fcb, eb, b3, WALL, BIAS);
    }
    // zero ST + SC + all per-layer SPA/SQA in one contiguous fill
    hipMemsetAsync(ST, 0, (size_t)(6144 + 1024 + 1536000) * sizeof(float), stream);
    gemm_tn<0,0><<<(N_ATOM+BM-1)/BM, 256, 0, stream>>>(atom_fea, OFEA, N_ATOM,
                                                       emb_W, OFEA, OFEA, AF, emb_b, X, AF);
    e_init<<<(NM*LDE+255)/256, 256, 0, stream>>>(nbr_fea, E48);

    for (int i = 0; i < NCONV; i++){
        float* STL = ST + i*2048;
        float* SPA = SPQ + (size_t)i*512000;
        float* SQA = SPA + 256000;

        {
            dim3 g((NM+127)/128, 4);
            gemm_fused<<<g, 256, 0, stream>>>(X, E48, nbr_idx,
                                              WALL + (size_t)i*512*LDA_T,
                                              BIAS + i*512, REST, STL, SPA, SQA);
        }
        bn3_pre<<<32, 256, 0, stream>>>(SPA, SQA, STL);
        consumer_k<<<N_ATOM, 256, 0, stream>>>(REST, STL, TB, E48,
                                               bn1_g + i*O1, bn1_b + i*O1,
                                               bne_g + i*OE, bne_b + i*OE,
                                               bn3_g + i*O1, bn3_b + i*O1);
        tb_stats_k<<<128, 64, 0, stream>>>(TB, STL+768, STL+832);
        x_update_k<<<(N_ATOM*AF+255)/256, 256, 0, stream>>>(X, TB, STL+768, STL+832,
                                                            bn2_g + i*AF, bn2_b + i*AF,
                                                            N_ATOM*AF);
    }

    // head: Z = softplus(softplus(X) @ fc1W^T + fc1b); pooled mean; out
    gemm_tn<1,1><<<(N_ATOM+BM-1)/BM, 256, 0, stream>>>(X, AF, N_ATOM, fc1W, AF, AF, HID,
                                                       fc1b, Z, HID);
    pool_out_k<<<NCRY, 128, 0, stream>>>(Z, site_seg, outW, outb, (float*)d_out);
}

// Round 6
// 355.834 us; speedup vs baseline: 2.9349x; 1.0960x over previous
//
#include <hip/hip_runtime.h>
#include <hip/hip_bf16.h>

// Problem constants
#define N_ATOM 2000
#define MNBR   12
#define OFEA   92
#define AF     64
#define BFEA   41
#define K1     169   // 2A+B
#define O1     128
#define OE     82
#define NM     24000
#define NCONV  3
#define HID    128
#define NCRY   64
#define EPS_BN 1e-5f

#define LDA_T  192   // bf16 weight leading dim (169 padded to 192)
#define LDH    512   // REST: [h(0..127)|he(128..209)|pad|P'(256..383)|Q'(384..511)]
#define LDSW   88    // LDS row pitch (ushorts) for MFMA tiles
#define LDE    48    // padded E stride (41 -> 48, float4-aligned rows)

typedef __bf16 bf16x8 __attribute__((ext_vector_type(8)));
typedef float  f32x4  __attribute__((ext_vector_type(4)));

__device__ __forceinline__ float sigmoidf_(float x){
    return __builtin_amdgcn_rcpf(1.f + __expf(-x));
}
__device__ __forceinline__ float softplusf_(float x){
    return fmaxf(x,0.f) + __logf(1.f + __expf(-fabsf(x)));
}
__device__ __forceinline__ uint4 pack_bf16_8(const float* v){
    __hip_bfloat16 o[8];
    #pragma unroll
    for (int j=0;j<8;j++) o[j] = __float2bfloat16(v[j]);
    return *(const uint4*)o;
}

// ================= bf16 MFMA GEMM with fused gather (A-tile from X/E48/idx)
// and fused BN statistics in the epilogue.
// STL layout (floats): S1A[0..255] S2A[256..511] S13[512..639] S23[640..767]
//                      S12[768..831] S22[832..895] S2P[896..1023] S2Q[1024..1151]
__global__ __launch_bounds__(256, 3)
void gemm_fused(const float* __restrict__ X,
                const float* __restrict__ E48,
                const int*   __restrict__ idx,
                const __hip_bfloat16* __restrict__ W,
                const float* __restrict__ bias,
                float* __restrict__ REST,
                float* __restrict__ STL,
                float* __restrict__ SPA,
                float* __restrict__ SQA)
{
    __shared__ unsigned short As[128][LDSW];
    __shared__ unsigned short Ws[128][LDSW];
    __shared__ float cs1[128];
    __shared__ float cs2[128];
    __shared__ float spa[12][128];   // per-atom P'/Q' row-sums (block spans <=12 atoms)

    const int tid  = threadIdx.x;
    const int row0 = blockIdx.x * 128;
    const int col0 = blockIdx.y * 128;
    const int w    = tid >> 6;
    const int l    = tid & 63;
    const int wm   = w >> 1, wn = w & 1;
    const int lrow = l & 15;
    const int quad = l >> 4;

    if (tid < 128){ cs1[tid] = 0.f; cs2[tid] = 0.f; }
    for (int ii = tid; ii < 12*128; ii += 256) spa[ii>>7][ii&127] = 0.f;

    f32x4 acc[4][4];
    #pragma unroll
    for (int i=0;i<4;i++)
        #pragma unroll
        for (int j=0;j<4;j++) acc[i][j] = (f32x4){0.f,0.f,0.f,0.f};

    #pragma unroll
    for (int it = 0; it < 3; ++it){
        const int k0 = it * 64;
        if (it) __syncthreads();
        #pragma unroll
        for (int j = 0; j < 4; ++j){
            int e  = tid + j*256;
            int r  = e >> 3;
            int kk = (e & 7) << 3;
            int grow = row0 + r;
            float v[8];
            #pragma unroll
            for (int q2=0;q2<8;q2++) v[q2] = 0.f;
            if (grow < NM){
                if (it == 2){
                    if (kk < LDE){
                        const float* s = E48 + (size_t)grow*LDE + kk;
                        float4 a0 = *(const float4*)s;
                        float4 a1 = *(const float4*)(s+4);
                        v[0]=a0.x; v[1]=a0.y; v[2]=a0.z; v[3]=a0.w;
                        v[4]=a1.x; v[5]=a1.y; v[6]=a1.z; v[7]=a1.w;
                    }
                } else {
                    const float* s = (it == 0)
                        ? X + (size_t)((unsigned)grow/12u)*AF + kk
                        : X + (size_t)idx[grow]*AF + kk;
                    float4 a0 = *(const float4*)s;
                    float4 a1 = *(const float4*)(s+4);
                    v[0]=a0.x; v[1]=a0.y; v[2]=a0.z; v[3]=a0.w;
                    v[4]=a1.x; v[5]=a1.y; v[6]=a1.z; v[7]=a1.w;
                }
            }
            *(uint4*)(&As[r][kk]) = pack_bf16_8(v);
            uint4 vw = *(const uint4*)(W + (size_t)(col0 + r)*LDA_T + k0 + kk);
            *(uint4*)(&Ws[r][kk]) = vw;
        }
        __syncthreads();
        #pragma unroll
        for (int ks = 0; ks < 2; ++ks){
            int koff = ks*32 + quad*8;
            bf16x8 a_[4], b_[4];
            #pragma unroll
            for (int mi=0;mi<4;mi++)
                a_[mi] = *(const bf16x8*)(&As[wm*64 + mi*16 + lrow][koff]);
            #pragma unroll
            for (int ni=0;ni<4;ni++)
                b_[ni] = *(const bf16x8*)(&Ws[wn*64 + ni*16 + lrow][koff]);
            #pragma unroll
            for (int mi=0;mi<4;mi++)
                #pragma unroll
                for (int ni=0;ni<4;ni++)
                    acc[mi][ni] = __builtin_amdgcn_mfma_f32_16x16x32_bf16(
                        a_[mi], b_[ni], acc[mi][ni], 0, 0, 0);
        }
    }

    // ---------------- epilogue: store + fused BN stats ----------------
    const bool isPQ = (col0 >= 256);
    const int atomBase = (unsigned)row0 / 12u;
    int rbase_[4], n0_[4], sp_[4];
    #pragma unroll
    for (int mi=0;mi<4;mi++){
        rbase_[mi] = row0 + wm*64 + mi*16 + quad*4;
        int n0 = (int)((unsigned)rbase_[mi] / 12u);
        n0_[mi] = n0;
        sp_[mi] = 12 - (rbase_[mi] - n0*12);
    }

    #pragma unroll
    for (int ni=0;ni<4;ni++){
        const int cl  = wn*64 + ni*16 + lrow;   // 0..127 within block
        const int col = col0 + cl;
        const float bv = bias[col];
        float s1 = 0.f, s2 = 0.f;
        #pragma unroll
        for (int mi=0;mi<4;mi++){
            const int rbase = rbase_[mi];
            float run0 = 0.f, run1 = 0.f;
            #pragma unroll
            for (int reg=0;reg<4;reg++){
                int grow = rbase + reg;
                if (grow < NM){
                    float vv = acc[mi][ni][reg] + bv;
                    if (col0 != 128 || col < 210)     // cols 210..255 dead
                        REST[(size_t)grow*LDH + col] = vv;
                    s1 += vv; s2 += vv*vv;
                    if (isPQ){
                        if (reg < sp_[mi]) run0 += vv; else run1 += vv;
                    }
                }
            }
            if (isPQ){
                if (run0 != 0.f) atomicAdd(&spa[n0_[mi]     - atomBase][cl], run0);
                if (run1 != 0.f) atomicAdd(&spa[n0_[mi] + 1 - atomBase][cl], run1);
            }
        }
        if (isPQ){
            atomicAdd(&cs2[cl], s2);
        } else {
            atomicAdd(&cs1[cl], s1);
            atomicAdd(&cs2[cl], s2);
        }
    }
    __syncthreads();
    if (!isPQ){
        if (tid < 128){
            atomicAdd(&STL[col0 + tid],       cs1[tid]);   // S1A
            atomicAdd(&STL[256 + col0 + tid], cs2[tid]);   // S2A
        }
    } else {
        if (tid < 128)
            atomicAdd(&STL[(col0 == 256 ? 896 : 1024) + tid], cs2[tid]); // S2P / S2Q
        float* SPQd = (col0 == 256) ? SPA : SQA;
        for (int ii = tid; ii < 12*128; ii += 256){
            int ai = ii >> 7, c2 = ii & 127;
            int na = atomBase + ai;
            float val = spa[ai][c2];
            if (val != 0.f && na < N_ATOM)
                atomicAdd(&SPQd[(size_t)na*128 + c2], val);
        }
    }
}

// ================= fold per-atom P/Q sums into closed-form BN3 sums
__global__ __launch_bounds__(256)
void bn3_pre(const float* __restrict__ SPA, const float* __restrict__ SQA,
             float* __restrict__ STL)
{
    const int c    = threadIdx.x & 127;
    const int half = threadIdx.x >> 7;
    float s1 = 0.f, sx = 0.f;
    for (int n = blockIdx.x*2 + half; n < N_ATOM; n += 64){
        float p = SPA[(size_t)n*128 + c];
        float q = SQA[(size_t)n*128 + c];
        s1 += p + q;
        sx += p * q;
    }
    atomicAdd(&STL[512 + c], 12.f*s1);   // S13
    atomicAdd(&STL[640 + c], 2.f*sx);    // S23 cross term
}

// ================= embedding: X[2000][64] = atom_fea[2000][92] @ emb_W^T + b
// 125 blocks x 16 atoms, weights staged in LDS, thread = (atom, 4 cols)
__global__ __launch_bounds__(256)
void emb_k(const float* __restrict__ A, const float* __restrict__ Wm,
           const float* __restrict__ b, float* __restrict__ X)
{
    __shared__ float Ws[64][93];
    __shared__ float As[16][93];
    const int t = threadIdx.x;
    const int n0 = blockIdx.x * 16;
    for (int i = t; i < 64*OFEA; i += 256){
        int c = i / OFEA, k = i % OFEA;
        Ws[c][k] = Wm[i];
    }
    for (int i = t; i < 16*OFEA; i += 256){
        int r = i / OFEA, k = i % OFEA;
        As[r][k] = A[(size_t)(n0 + r)*OFEA + k];
    }
    __syncthreads();
    const int r  = t >> 4;          // 0..15
    const int c0 = (t & 15) * 4;    // 0..60
    float a0=0.f, a1=0.f, a2=0.f, a3=0.f;
    for (int k = 0; k < OFEA; ++k){
        float av = As[r][k];
        a0 += av * Ws[c0+0][k];
        a1 += av * Ws[c0+1][k];
        a2 += av * Ws[c0+2][k];
        a3 += av * Ws[c0+3][k];
    }
    size_t o = (size_t)(n0 + r)*AF + c0;
    X[o+0] = a0 + b[c0+0];
    X[o+1] = a1 + b[c0+1];
    X[o+2] = a2 + b[c0+2];
    X[o+3] = a3 + b[c0+3];
}

// ================= head: Z[2000][128] = softplus(softplus(X) @ fc1W^T + b)
// 125 blocks x 16 atoms, thread = (atom, 8 cols)
__global__ __launch_bounds__(256)
void head_k(const float* __restrict__ X, const float* __restrict__ Wm,
            const float* __restrict__ b, float* __restrict__ Z)
{
    __shared__ float Ws[128][65];
    __shared__ float Xs[16][65];
    const int t = threadIdx.x;
    const int n0 = blockIdx.x * 16;
    for (int i = t; i < 128*AF; i += 256){
        int c = i >> 6, k = i & 63;
        Ws[c][k] = Wm[i];
    }
    for (int i = t; i < 16*AF; i += 256){
        int r = i >> 6, k = i & 63;
        Xs[r][k] = softplusf_(X[(size_t)(n0 + r)*AF + k]);
    }
    __syncthreads();
    const int r  = t >> 4;          // 0..15
    const int c0 = (t & 15) * 8;    // 0..120
    float acc[8];
    #pragma unroll
    for (int j=0;j<8;j++) acc[j] = 0.f;
    for (int k = 0; k < AF; ++k){
        float xv = Xs[r][k];
        #pragma unroll
        for (int j=0;j<8;j++)
            acc[j] += xv * Ws[c0+j][k];
    }
    size_t o = (size_t)(n0 + r)*HID + c0;
    #pragma unroll
    for (int j=0;j<8;j++)
        Z[o+j] = softplusf_(acc[j] + b[c0+j]);
}

// ================= pack weights (bf16) + bias (fp32).
__global__ void pack_all(const float* __restrict__ fcW, const float* __restrict__ eW,
                         const float* __restrict__ W3, const float* __restrict__ fcb,
                         const float* __restrict__ eb, const float* __restrict__ b3,
                         __hip_bfloat16* __restrict__ WALL, float* __restrict__ BIAS)
{
    int i = blockIdx.x*blockDim.x + threadIdx.x;
    const int nW = NCONV*512*LDA_T;
    if (i < nW){
        int ll = i/(512*LDA_T), rem = i%(512*LDA_T);
        int c = rem/LDA_T, k = rem%LDA_T;
        float v = 0.f;
        if (c < O1){
            if (k < K1) v = fcW[((size_t)ll*O1 + c)*K1 + k];
        } else if (c < O1+OE){
            if (k < K1) v = eW[((size_t)ll*OE + (c-O1))*K1 + k];
        } else if (c >= 256 && c < 384){
            int o = c - 256;
            const float* W3l = W3 + (size_t)ll*O1*274;
            if (k < AF)                        v = 0.5f * W3l[(size_t)o*274 + k];          // Wa/2
            else if (k < 2*AF)                 v = W3l[(size_t)o*274 + k];                 // Wj
            else if (k < K1)                   v = W3l[(size_t)o*274 + 192 + (k-128)];     // Wij
        } else if (c >= 384){
            int o = c - 384;
            const float* W3l = W3 + (size_t)ll*O1*274;
            if (k < AF)                        v = 0.5f * W3l[(size_t)o*274 + k];          // Wa/2
            else if (k < 2*AF)                 v = W3l[(size_t)o*274 + k + AF];            // Wl
            else if (k < K1)                   v = W3l[(size_t)o*274 + 233 + (k-128)];     // Wil
        }
        WALL[i] = __float2bfloat16(v);
    } else if (i < nW + NCONV*512){
        int m = i - nW;
        int ll = m/512, c = m%512;
        float v = 0.f;
        if (c < O1)         v = fcb[ll*O1 + c];
        else if (c < O1+OE) v = eb[ll*OE + (c-O1)];
        else if (c >= 256)  v = 0.5f * b3[ll*O1 + ((c-256)&127)];
        BIAS[m] = v;
    }
}

// ================= nbr_fea [NM][41] -> E48 [NM][48] (zero-padded)
__global__ void e_init(const float* __restrict__ nbr, float* __restrict__ E48)
{
    int i = blockIdx.x*blockDim.x + threadIdx.x;
    if (i >= NM*LDE) return;
    int r = i / LDE, k = i % LDE;
    E48[i] = (k < BFEA) ? nbr[(size_t)r*BFEA + k] : 0.f;
}

// ================= consumer: block = atom, 256 threads (4 waves x 3 m's each).
// Inlined BN finalize; factored-exponential 3-body inner loop.
__global__ __launch_bounds__(256)
void consumer_k(const float* __restrict__ REST, const float* __restrict__ STL,
                float* __restrict__ TB, float* __restrict__ E48,
                const float* __restrict__ g1, const float* __restrict__ b1,
                const float* __restrict__ ge, const float* __restrict__ be,
                const float* __restrict__ g3, const float* __restrict__ b3b)
{
    __shared__ float red[256];
    __shared__ float scA[210], shA[210], sc3v[128], sh3v[128];
    const int n = blockIdx.x;
    const int t = threadIdx.x;
    const int a = t & 63;
    const int g = t >> 6;     // 0..3, each owns 3 m's

    // ---- BN finalize (redundant per block; trivial ALU) ----
    if (t < 210){
        float mean = STL[t]*(1.f/NM);
        float var  = fmaxf(STL[256+t]*(1.f/NM) - mean*mean, 0.f);
        float gg = (t < O1) ? g1[t] : ge[t-O1];
        float bb = (t < O1) ? b1[t] : be[t-O1];
        float sc = gg * rsqrtf(var + EPS_BN);
        scA[t] = sc; shA[t] = bb - sc*mean;
    }
    if (t < 128){
        float inv  = 1.f/((float)NM*MNBR);
        float mean = STL[512+t]*inv;
        float ex2  = (STL[640+t] + 12.f*(STL[896+t] + STL[1024+t]))*inv;
        float var  = fmaxf(ex2 - mean*mean, 0.f);
        float sc = g3[t] * rsqrtf(var + EPS_BN);
        sc3v[t] = sc; sh3v[t] = b3b[t] - sc*mean;
    }
    __syncthreads();

    const float* base = REST + (size_t)n*MNBR*LDH;
    const float s3lo = sc3v[a],  s3hi = sc3v[64+a];
    const float t3lo = sh3v[a],  t3hi = sh3v[64+a];

    // factored exponentials for all 12 l: e^{-Qa[l]}, e^{+Qb[l]}
    float Ea[MNBR], Fb[MNBR];
    #pragma unroll
    for (int m=0;m<MNBR;m++){
        const float* row = base + (size_t)m*LDH;
        Ea[m] = __expf(-(s3lo*row[384+a]));
        Fb[m] = __expf( (s3hi*row[448+a]));
    }
    const float sha = scA[a],    tha = shA[a];
    const float shb = scA[64+a], thb = shA[64+a];
    float acc = 0.f;
    #pragma unroll
    for (int j=0;j<3;j++){
        const float* row = base + (size_t)(g*3+j)*LDH;
        // 2-body term for this m
        acc += sigmoidf_(sha*row[a]+tha) * softplusf_(shb*row[64+a]+thb);
        // 3-body: sigma(ua+Qa[l]) * softplus(ub+Qb[l]) with factored exps
        float ua = s3lo*row[256+a] + t3lo;
        float ub = s3hi*row[320+a] + t3hi;
        float Em = __expf(-ua);
        float Fm = __expf(ub);
        #pragma unroll
        for (int l2=0;l2<MNBR;l2++){
            float s = __builtin_amdgcn_rcpf(1.f + Em*Ea[l2]);
            float p = __logf(1.f + Fm*Fb[l2]);
            acc += s*p;
        }
    }
    red[t] = acc;
    __syncthreads();
    if (t < 64)
        TB[(size_t)n*AF + t] = red[t] + red[64+t] + red[128+t] + red[192+t];
    // edge update on padded E48
    for (int idx = t; idx < MNBR*BFEA; idx += 256){
        int m = idx / BFEA, b = idx % BFEA;
        const float* row = base + (size_t)m*LDH;
        float u = scA[O1+b]*row[O1+b]   + shA[O1+b];
        float v = scA[169+b]*row[169+b] + shA[169+b];
        E48[((size_t)n*MNBR + m)*LDE + b] += sigmoidf_(u) * softplusf_(v);
    }
}

// ================= per-column sum/sumsq for TB (low-contention)
__global__ __launch_bounds__(64)
void tb_stats_k(const float* __restrict__ TB,
                float* __restrict__ S1, float* __restrict__ S2)
{
    int t = threadIdx.x;
    float s1 = 0.f, s2 = 0.f;
    for (int r = blockIdx.x; r < N_ATOM; r += gridDim.x){
        float v = TB[(size_t)r*AF + t];
        s1 += v; s2 += v*v;
    }
    atomicAdd(&S1[t], s1);
    atomicAdd(&S2[t], s2);
}

// ================= x = softplus(x + bn2(TB)), inline finalize
__global__ void x_update_k(float* __restrict__ X, const float* __restrict__ TB,
                           const float* __restrict__ S12, const float* __restrict__ S22,
                           const float* __restrict__ g2, const float* __restrict__ b2,
                           int total)
{
    int i = blockIdx.x*blockDim.x + threadIdx.x;
    if (i >= total) return;
    int a = i & (AF-1);
    float mean = S12[a]*(1.f/N_ATOM);
    float var  = fmaxf(S22[a]*(1.f/N_ATOM) - mean*mean, 0.f);
    float sc = g2[a]*rsqrtf(var + EPS_BN);
    X[i] = softplusf_(X[i] + sc*TB[i] + (b2[a] - sc*mean));
}

// ================= pooled mean per crystal + final dot
__global__ __launch_bounds__(128)
void pool_out_k(const float* __restrict__ Z, const int* __restrict__ seg,
                const float* __restrict__ outW, const float* __restrict__ outb,
                float* __restrict__ out)
{
    __shared__ float red[128];
    const int c = blockIdx.x;
    const int h = threadIdx.x;
    int l0, l1;
    {
        int l=0, r=N_ATOM;
        while (l<r){ int m=(l+r)>>1; if (seg[m] < c) l=m+1; else r=m; }
        l0 = l;
        l=l0; r=N_ATOM;
        while (l<r){ int m=(l+r)>>1; if (seg[m] < c+1) l=m+1; else r=m; }
        l1 = l;
    }
    float s = 0.f;
    for (int n = l0; n < l1; ++n) s += Z[(size_t)n*HID + h];
    float cnt = fmaxf((float)(l1-l0), 1.f);
    red[h] = (s/cnt) * outW[h];
    __syncthreads();
    for (int off=64; off>0; off>>=1){
        if (h < off) red[h] += red[h+off];
        __syncthreads();
    }
    if (h == 0) out[c] = red[0] + outb[0];
}

extern "C" void kernel_launch(void* const* d_in, const int* in_sizes, int n_in,
                              void* d_out, int out_size, void* d_ws, size_t ws_size,
                              hipStream_t stream)
{
    const float* atom_fea = (const float*)d_in[0];
    const float* nbr_fea  = (const float*)d_in[1];
    const int*   nbr_idx  = (const int*)d_in[2];
    const int*   site_seg = (const int*)d_in[3];
    const float* emb_W = (const float*)d_in[4];
    const float* emb_b = (const float*)d_in[5];
    const float* fcW   = (const float*)d_in[6];
    const float* fcb   = (const float*)d_in[7];
    const float* bn1_g = (const float*)d_in[8];
    const float* bn1_b = (const float*)d_in[9];
    const float* bn2_g = (const float*)d_in[10];
    const float* bn2_b = (const float*)d_in[11];
    const float* eW    = (const float*)d_in[12];
    const float* eb    = (const float*)d_in[13];
    const float* bne_g = (const float*)d_in[14];
    const float* bne_b = (const float*)d_in[15];
    const float* W3    = (const float*)d_in[16];
    const float* b3    = (const float*)d_in[17];
    const float* bn3_g = (const float*)d_in[18];
    const float* bn3_b = (const float*)d_in[19];
    const float* fc1W  = (const float*)d_in[20];
    const float* fc1b  = (const float*)d_in[21];
    const float* outW  = (const float*)d_in[22];
    const float* outb  = (const float*)d_in[23];

    // workspace layout (float units)
    float* ws   = (float*)d_ws;
    float* X    = ws;                          // 128,000
    float* E48  = ws + 128000;                 // 1,152,000 -> 1,280,000
    float* REST = ws + 1280000;                // 24000*512 = 12,288,000
    float* TB   = ws + 13568000;               // 128,000
    float* Z    = ws + 13696000;               // 256,000
    float* ST   = ws + 13952000;               // 3*2048 = 6,144
    float* SCu  = ws + 13958144;               // 1,024 (unused, keeps offsets)
    float* SPQ  = ws + 13959168;               // 3 * 2 * 256,000 = 1,536,000
    __hip_bfloat16* WALL = (__hip_bfloat16*)(ws + 15495168); // 3*512*192 bf16
    float* BIAS = ws + 15642624;               // 1,536
    (void)SCu;

    {
        int tot = NCONV*512*LDA_T + NCONV*512;
        pack_all<<<(tot+255)/256, 256, 0, stream>>>(fcW, eW, W3, fcb, eb, b3, WALL, BIAS);
    }
    // zero ST + SC + all per-layer SPA/SQA in one contiguous fill
    hipMemsetAsync(ST, 0, (size_t)(6144 + 1024 + 1536000) * sizeof(float), stream);
    emb_k<<<N_ATOM/16, 256, 0, stream>>>(atom_fea, emb_W, emb_b, X);
    e_init<<<(NM*LDE+255)/256, 256, 0, stream>>>(nbr_fea, E48);

    for (int i = 0; i < NCONV; i++){
        float* STL = ST + i*2048;
        float* SPA = SPQ + (size_t)i*512000;
        float* SQA = SPA + 256000;

        {
            dim3 g((NM+127)/128, 4);
            gemm_fused<<<g, 256, 0, stream>>>(X, E48, nbr_idx,
                                              WALL + (size_t)i*512*LDA_T,
                                              BIAS + i*512, REST, STL, SPA, SQA);
        }
        bn3_pre<<<32, 256, 0, stream>>>(SPA, SQA, STL);
        consumer_k<<<N_ATOM, 256, 0, stream>>>(REST, STL, TB, E48,
                                               bn1_g + i*O1, bn1_b + i*O1,
                                               bne_g + i*OE, bne_b + i*OE,
                                               bn3_g + i*O1, bn3_b + i*O1);
        tb_stats_k<<<128, 64, 0, stream>>>(TB, STL+768, STL+832);
        x_update_k<<<(N_ATOM*AF+255)/256, 256, 0, stream>>>(X, TB, STL+768, STL+832,
                                                            bn2_g + i*AF, bn2_b + i*AF,
                                                            N_ATOM*AF);
    }

    // head: Z = softplus(softplus(X) @ fc1W^T + fc1b); pooled mean; out
    head_k<<<N_ATOM/16, 256, 0, stream>>>(X, fc1W, fc1b, Z);
    pool_out_k<<<NCRY, 128, 0, stream>>>(Z, site_seg, outW, outb, (float*)d_out);
}

// Round 8
// 350.898 us; speedup vs baseline: 2.9762x; 1.0141x over previous
//
#include <hip/hip_runtime.h>
#include <hip/hip_bf16.h>

// Problem constants
#define N_ATOM 2000
#define MNBR   12
#define OFEA   92
#define AF     64
#define BFEA   41
#define K1     169   // 2A+B
#define O1     128
#define OE     82
#define NM     24000
#define NCONV  3
#define HID    128
#define NCRY   64
#define EPS_BN 1e-5f

#define LDA_T  192   // bf16 weight leading dim (169 padded to 192)
#define LDH    512   // REST: [h(0..127)|he(128..209)|pad|P'(256..383)|Q'(384..511)]
#define LDSW   88    // LDS row pitch (ushorts) for MFMA tiles
#define LDE    48    // padded E stride (41 -> 48)

typedef __bf16 bf16x8 __attribute__((ext_vector_type(8)));
typedef float  f32x4  __attribute__((ext_vector_type(4)));

__device__ __forceinline__ float sigmoidf_(float x){
    return __builtin_amdgcn_rcpf(1.f + __expf(-x));
}
__device__ __forceinline__ float softplusf_(float x){
    return fmaxf(x,0.f) + __logf(1.f + __expf(-fabsf(x)));
}

// ================= bf16 MFMA GEMM: A-tile gathered directly from bf16 mirrors
// (Xb / E48b / idx); fused BN statistics in the epilogue.
// STL layout (floats): S1A[0..255] S2A[256..511] S13[512..639] S23[640..767]
//   S12[768..831] S22[832..895] S2P[896..1023] S2Q[1024..1151] cnt[1200]
__global__ __launch_bounds__(256, 3)
void gemm_fused(const unsigned short* __restrict__ Xb,
                const unsigned short* __restrict__ E48b,
                const int*   __restrict__ idx,
                const __hip_bfloat16* __restrict__ W,
                const float* __restrict__ bias,
                float* __restrict__ REST,
                float* __restrict__ STL,
                float* __restrict__ SPA,
                float* __restrict__ SQA)
{
    __shared__ unsigned short As[128][LDSW];
    __shared__ unsigned short Ws[128][LDSW];
    __shared__ float cs1[128];
    __shared__ float cs2[128];
    __shared__ float spa[12][128];   // per-atom P'/Q' row-sums (block spans <=12 atoms)

    const int tid  = threadIdx.x;
    const int row0 = blockIdx.x * 128;
    const int col0 = blockIdx.y * 128;
    const int w    = tid >> 6;
    const int l    = tid & 63;
    const int wm   = w >> 1, wn = w & 1;
    const int lrow = l & 15;
    const int quad = l >> 4;

    if (tid < 128){ cs1[tid] = 0.f; cs2[tid] = 0.f; }
    for (int ii = tid; ii < 12*128; ii += 256) spa[ii>>7][ii&127] = 0.f;

    f32x4 acc[4][4];
    #pragma unroll
    for (int i=0;i<4;i++)
        #pragma unroll
        for (int j=0;j<4;j++) acc[i][j] = (f32x4){0.f,0.f,0.f,0.f};

    #pragma unroll
    for (int it = 0; it < 3; ++it){
        const int k0 = it * 64;
        if (it) __syncthreads();
        #pragma unroll
        for (int j = 0; j < 4; ++j){
            int e   = tid + j*256;
            int r   = e >> 3;
            int kk8 = (e & 7);            // group of 8 bf16
            int grow = row0 + r;
            uint4 va = make_uint4(0,0,0,0);
            if (grow < NM){
                if (it == 2){
                    if (kk8 < 6)
                        va = *(const uint4*)(E48b + (size_t)grow*LDE + kk8*8);
                } else {
                    const unsigned short* s = (it == 0)
                        ? Xb + (size_t)((unsigned)grow/12u)*AF + kk8*8
                        : Xb + (size_t)idx[grow]*AF + kk8*8;
                    va = *(const uint4*)s;
                }
            }
            *(uint4*)(&As[r][kk8*8]) = va;
            uint4 vw = *(const uint4*)(W + (size_t)(col0 + r)*LDA_T + k0 + kk8*8);
            *(uint4*)(&Ws[r][kk8*8]) = vw;
        }
        __syncthreads();
        #pragma unroll
        for (int ks = 0; ks < 2; ++ks){
            int koff = ks*32 + quad*8;
            bf16x8 a_[4], b_[4];
            #pragma unroll
            for (int mi=0;mi<4;mi++)
                a_[mi] = *(const bf16x8*)(&As[wm*64 + mi*16 + lrow][koff]);
            #pragma unroll
            for (int ni=0;ni<4;ni++)
                b_[ni] = *(const bf16x8*)(&Ws[wn*64 + ni*16 + lrow][koff]);
            #pragma unroll
            for (int mi=0;mi<4;mi++)
                #pragma unroll
                for (int ni=0;ni<4;ni++)
                    acc[mi][ni] = __builtin_amdgcn_mfma_f32_16x16x32_bf16(
                        a_[mi], b_[ni], acc[mi][ni], 0, 0, 0);
        }
    }

    // ---------------- epilogue: store + fused BN stats ----------------
    const bool isPQ = (col0 >= 256);
    const int atomBase = (unsigned)row0 / 12u;
    int rbase_[4], n0_[4], sp_[4];
    #pragma unroll
    for (int mi=0;mi<4;mi++){
        rbase_[mi] = row0 + wm*64 + mi*16 + quad*4;
        int n0 = (int)((unsigned)rbase_[mi] / 12u);
        n0_[mi] = n0;
        sp_[mi] = 12 - (rbase_[mi] - n0*12);
    }

    #pragma unroll
    for (int ni=0;ni<4;ni++){
        const int cl  = wn*64 + ni*16 + lrow;   // 0..127 within block
        const int col = col0 + cl;
        const float bv = bias[col];
        float s1 = 0.f, s2 = 0.f;
        #pragma unroll
        for (int mi=0;mi<4;mi++){
            const int rbase = rbase_[mi];
            float run0 = 0.f, run1 = 0.f;
            #pragma unroll
            for (int reg=0;reg<4;reg++){
                int grow = rbase + reg;
                if (grow < NM){
                    float vv = acc[mi][ni][reg] + bv;
                    if (col0 != 128 || col < 210)     // cols 210..255 dead
                        REST[(size_t)grow*LDH + col] = vv;
                    s1 += vv; s2 += vv*vv;
                    if (isPQ){
                        if (reg < sp_[mi]) run0 += vv; else run1 += vv;
                    }
                }
            }
            if (isPQ){
                if (run0 != 0.f) atomicAdd(&spa[n0_[mi]     - atomBase][cl], run0);
                if (run1 != 0.f) atomicAdd(&spa[n0_[mi] + 1 - atomBase][cl], run1);
            }
        }
        if (isPQ){
            atomicAdd(&cs2[cl], s2);
        } else {
            atomicAdd(&cs1[cl], s1);
            atomicAdd(&cs2[cl], s2);
        }
    }
    __syncthreads();
    if (!isPQ){
        if (tid < 128){
            atomicAdd(&STL[col0 + tid],       cs1[tid]);   // S1A
            atomicAdd(&STL[256 + col0 + tid], cs2[tid]);   // S2A
        }
    } else {
        if (tid < 128)
            atomicAdd(&STL[(col0 == 256 ? 896 : 1024) + tid], cs2[tid]); // S2P / S2Q
        float* SPQd = (col0 == 256) ? SPA : SQA;
        for (int ii = tid; ii < 12*128; ii += 256){
            int ai = ii >> 7, c2 = ii & 127;
            int na = atomBase + ai;
            float val = spa[ai][c2];
            if (val != 0.f && na < N_ATOM)
                atomicAdd(&SPQd[(size_t)na*128 + c2], val);
        }
    }
}

// ================= fold per-atom P/Q sums into closed-form BN3 sums
__global__ __launch_bounds__(256)
void bn3_pre(const float* __restrict__ SPA, const float* __restrict__ SQA,
             float* __restrict__ STL)
{
    const int c    = threadIdx.x & 127;
    const int half = threadIdx.x >> 7;
    float s1 = 0.f, sx = 0.f;
    for (int n = blockIdx.x*2 + half; n < N_ATOM; n += 250){
        float p = SPA[(size_t)n*128 + c];
        float q = SQA[(size_t)n*128 + c];
        s1 += p + q;
        sx += p * q;
    }
    atomicAdd(&STL[512 + c], 12.f*s1);   // S13
    atomicAdd(&STL[640 + c], 2.f*sx);    // S23 cross term
}

// ================= embedding: X[2000][64] = atom_fea @ emb_W^T + b (fp32 + bf16 mirror)
__global__ __launch_bounds__(256)
void emb_k(const float* __restrict__ A, const float* __restrict__ Wm,
           const float* __restrict__ b, float* __restrict__ X,
           __hip_bfloat16* __restrict__ Xb)
{
    __shared__ float Ws[64][93];
    __shared__ float As[16][93];
    const int t = threadIdx.x;
    const int n0 = blockIdx.x * 16;
    for (int i = t; i < 64*OFEA; i += 256){
        int c = i / OFEA, k = i % OFEA;
        Ws[c][k] = Wm[i];
    }
    for (int i = t; i < 16*OFEA; i += 256){
        int r = i / OFEA, k = i % OFEA;
        As[r][k] = A[(size_t)(n0 + r)*OFEA + k];
    }
    __syncthreads();
    const int r  = t >> 4;
    const int c0 = (t & 15) * 4;
    float a0=0.f, a1=0.f, a2=0.f, a3=0.f;
    for (int k = 0; k < OFEA; ++k){
        float av = As[r][k];
        a0 += av * Ws[c0+0][k];
        a1 += av * Ws[c0+1][k];
        a2 += av * Ws[c0+2][k];
        a3 += av * Ws[c0+3][k];
    }
    size_t o = (size_t)(n0 + r)*AF + c0;
    float v0 = a0 + b[c0+0], v1 = a1 + b[c0+1];
    float v2 = a2 + b[c0+2], v3 = a3 + b[c0+3];
    X[o+0] = v0; X[o+1] = v1; X[o+2] = v2; X[o+3] = v3;
    Xb[o+0] = __float2bfloat16(v0); Xb[o+1] = __float2bfloat16(v1);
    Xb[o+2] = __float2bfloat16(v2); Xb[o+3] = __float2bfloat16(v3);
}

// ================= head: Z[2000][128] = softplus(softplus(X) @ fc1W^T + b)
__global__ __launch_bounds__(256)
void head_k(const float* __restrict__ X, const float* __restrict__ Wm,
            const float* __restrict__ b, float* __restrict__ Z)
{
    __shared__ float Ws[128][65];
    __shared__ float Xs[16][65];
    const int t = threadIdx.x;
    const int n0 = blockIdx.x * 16;
    for (int i = t; i < 128*AF; i += 256){
        int c = i >> 6, k = i & 63;
        Ws[c][k] = Wm[i];
    }
    for (int i = t; i < 16*AF; i += 256){
        int r = i >> 6, k = i & 63;
        Xs[r][k] = softplusf_(X[(size_t)(n0 + r)*AF + k]);
    }
    __syncthreads();
    const int r  = t >> 4;
    const int c0 = (t & 15) * 8;
    float acc[8];
    #pragma unroll
    for (int j=0;j<8;j++) acc[j] = 0.f;
    for (int k = 0; k < AF; ++k){
        float xv = Xs[r][k];
        #pragma unroll
        for (int j=0;j<8;j++)
            acc[j] += xv * Ws[c0+j][k];
    }
    size_t o = (size_t)(n0 + r)*HID + c0;
    #pragma unroll
    for (int j=0;j<8;j++)
        Z[o+j] = softplusf_(acc[j] + b[c0+j]);
}

// ================= prologue: weight pack + bias + E48/E48b init + stat zeroing
// flat index space: [0,nW) pack, [nW,nW+1536) bias, then e_init, then zero
__global__ void prologue_k(const float* __restrict__ fcW, const float* __restrict__ eW,
                           const float* __restrict__ W3, const float* __restrict__ fcb,
                           const float* __restrict__ eb, const float* __restrict__ b3,
                           const float* __restrict__ nbr,
                           __hip_bfloat16* __restrict__ WALL, float* __restrict__ BIAS,
                           float* __restrict__ E48, __hip_bfloat16* __restrict__ E48b,
                           float* __restrict__ ZR)
{
    int i = blockIdx.x*blockDim.x + threadIdx.x;
    const int nW = NCONV*512*LDA_T;           // 294912
    const int nB = NCONV*512;                 // 1536
    const int nE = NM*LDE;                    // 1152000
    if (i < nW){
        int ll = i/(512*LDA_T), rem = i%(512*LDA_T);
        int c = rem/LDA_T, k = rem%LDA_T;
        float v = 0.f;
        if (c < O1){
            if (k < K1) v = fcW[((size_t)ll*O1 + c)*K1 + k];
        } else if (c < O1+OE){
            if (k < K1) v = eW[((size_t)ll*OE + (c-O1))*K1 + k];
        } else if (c >= 256 && c < 384){
            int o = c - 256;
            const float* W3l = W3 + (size_t)ll*O1*274;
            if (k < AF)                        v = 0.5f * W3l[(size_t)o*274 + k];          // Wa/2
            else if (k < 2*AF)                 v = W3l[(size_t)o*274 + k];                 // Wj
            else if (k < K1)                   v = W3l[(size_t)o*274 + 192 + (k-128)];     // Wij
        } else if (c >= 384){
            int o = c - 384;
            const float* W3l = W3 + (size_t)ll*O1*274;
            if (k < AF)                        v = 0.5f * W3l[(size_t)o*274 + k];          // Wa/2
            else if (k < 2*AF)                 v = W3l[(size_t)o*274 + k + AF];            // Wl
            else if (k < K1)                   v = W3l[(size_t)o*274 + 233 + (k-128)];     // Wil
        }
        WALL[i] = __float2bfloat16(v);
    } else if (i < nW + nB){
        int m = i - nW;
        int ll = m/512, c = m%512;
        float v = 0.f;
        if (c < O1)         v = fcb[ll*O1 + c];
        else if (c < O1+OE) v = eb[ll*OE + (c-O1)];
        else if (c >= 256)  v = 0.5f * b3[ll*O1 + ((c-256)&127)];
        BIAS[m] = v;
    } else if (i < nW + nB + nE){
        int j = i - (nW + nB);
        int r = j / LDE, k = j % LDE;
        float v = (k < BFEA) ? nbr[(size_t)r*BFEA + k] : 0.f;
        E48[j]  = v;
        E48b[j] = __float2bfloat16(v);
    } else {
        int j = i - (nW + nB + nE);     // < 1,543,168
        ZR[j] = 0.f;
    }
}

// ================= consumer: block = atom, 256 threads (4 waves x 3 m's each).
// Inlined BN finalize; factored-exponential 3-body inner loop; bf16 E mirror.
__global__ __launch_bounds__(256)
void consumer_k(const float* __restrict__ REST, const float* __restrict__ STL,
                float* __restrict__ TB, float* __restrict__ E48,
                __hip_bfloat16* __restrict__ E48b,
                const float* __restrict__ g1, const float* __restrict__ b1,
                const float* __restrict__ ge, const float* __restrict__ be,
                const float* __restrict__ g3, const float* __restrict__ b3b)
{
    __shared__ float red[256];
    __shared__ float scA[210], shA[210], sc3v[128], sh3v[128];
    const int n = blockIdx.x;
    const int t = threadIdx.x;
    const int a = t & 63;
    const int g = t >> 6;     // 0..3, each owns 3 m's

    // ---- BN finalize (redundant per block; trivial ALU) ----
    if (t < 210){
        float mean = STL[t]*(1.f/NM);
        float var  = fmaxf(STL[256+t]*(1.f/NM) - mean*mean, 0.f);
        float gg = (t < O1) ? g1[t] : ge[t-O1];
        float bb = (t < O1) ? b1[t] : be[t-O1];
        float sc = gg * rsqrtf(var + EPS_BN);
        scA[t] = sc; shA[t] = bb - sc*mean;
    }
    if (t < 128){
        float inv  = 1.f/((float)NM*MNBR);
        float mean = STL[512+t]*inv;
        float ex2  = (STL[640+t] + 12.f*(STL[896+t] + STL[1024+t]))*inv;
        float var  = fmaxf(ex2 - mean*mean, 0.f);
        float sc = g3[t] * rsqrtf(var + EPS_BN);
        sc3v[t] = sc; sh3v[t] = b3b[t] - sc*mean;
    }
    __syncthreads();

    const float* base = REST + (size_t)n*MNBR*LDH;
    const float s3lo = sc3v[a],  s3hi = sc3v[64+a];
    const float t3lo = sh3v[a],  t3hi = sh3v[64+a];

    float Ea[MNBR], Fb[MNBR];
    #pragma unroll
    for (int m=0;m<MNBR;m++){
        const float* row = base + (size_t)m*LDH;
        Ea[m] = __expf(-(s3lo*row[384+a]));
        Fb[m] = __expf( (s3hi*row[448+a]));
    }
    const float sha = scA[a],    tha = shA[a];
    const float shb = scA[64+a], thb = shA[64+a];
    float acc = 0.f;
    #pragma unroll
    for (int j=0;j<3;j++){
        const float* row = base + (size_t)(g*3+j)*LDH;
        acc += sigmoidf_(sha*row[a]+tha) * softplusf_(shb*row[64+a]+thb);
        float ua = s3lo*row[256+a] + t3lo;
        float ub = s3hi*row[320+a] + t3hi;
        float Em = __expf(-ua);
        float Fm = __expf(ub);
        #pragma unroll
        for (int l2=0;l2<MNBR;l2++){
            float s = __builtin_amdgcn_rcpf(1.f + Em*Ea[l2]);
            float p = __logf(1.f + Fm*Fb[l2]);
            acc += s*p;
        }
    }
    red[t] = acc;
    __syncthreads();
    if (t < 64)
        TB[(size_t)n*AF + t] = red[t] + red[64+t] + red[128+t] + red[192+t];
    // edge update on padded E48 (+bf16 mirror for next layer's GEMM)
    for (int idx = t; idx < MNBR*BFEA; idx += 256){
        int m = idx / BFEA, b = idx % BFEA;
        const float* row = base + (size_t)m*LDH;
        float u = scA[O1+b]*row[O1+b]   + shA[O1+b];
        float v = scA[169+b]*row[169+b] + shA[169+b];
        size_t eo = ((size_t)n*MNBR + m)*LDE + b;
        float nv = E48[eo] + sigmoidf_(u) * softplusf_(v);
        E48[eo]  = nv;
        E48b[eo] = __float2bfloat16(nv);
    }
}

// ================= merged TB stats + x update (64 blocks, internal counter sync)
__global__ __launch_bounds__(256)
void xupd_k(float* __restrict__ X, __hip_bfloat16* __restrict__ Xb,
            const float* __restrict__ TB, float* __restrict__ STL,
            const float* __restrict__ g2, const float* __restrict__ b2)
{
    __shared__ float r1[256], r2[256];
    const int t = threadIdx.x;
    const int a = t & 63, rg = t >> 6;
    float s1 = 0.f, s2 = 0.f;
    for (int r = blockIdx.x*4 + rg; r < N_ATOM; r += 256){
        float v = TB[(size_t)r*AF + a];
        s1 += v; s2 += v*v;
    }
    r1[t] = s1; r2[t] = s2;
    __syncthreads();
    if (t < 64){
        s1 = r1[t]+r1[64+t]+r1[128+t]+r1[192+t];
        s2 = r2[t]+r2[64+t]+r2[128+t]+r2[192+t];
        atomicAdd(&STL[768+t], s1);
        atomicAdd(&STL[832+t], s2);
    }
    __syncthreads();
    if (t == 0){
        unsigned* cnt = (unsigned*)&STL[1200];
        __hip_atomic_fetch_add(cnt, 1u, __ATOMIC_ACQ_REL, __HIP_MEMORY_SCOPE_AGENT);
        while (__hip_atomic_load(cnt, __ATOMIC_ACQUIRE, __HIP_MEMORY_SCOPE_AGENT) < 64u)
            __builtin_amdgcn_s_sleep(2);
    }
    __syncthreads();
    float sA = __hip_atomic_load(&STL[768+a], __ATOMIC_RELAXED, __HIP_MEMORY_SCOPE_AGENT);
    float sB = __hip_atomic_load(&STL[832+a], __ATOMIC_RELAXED, __HIP_MEMORY_SCOPE_AGENT);
    float mean = sA*(1.f/N_ATOM);
    float var  = fmaxf(sB*(1.f/N_ATOM) - mean*mean, 0.f);
    float sc = g2[a]*rsqrtf(var + EPS_BN);
    float sh = b2[a] - sc*mean;
    for (int i = blockIdx.x*256 + t; i < N_ATOM*AF; i += 64*256){
        float v = softplusf_(X[i] + sc*TB[i] + sh);
        X[i]  = v;
        Xb[i] = __float2bfloat16(v);
    }
}

// ================= pooled mean per crystal + final dot
__global__ __launch_bounds__(128)
void pool_out_k(const float* __restrict__ Z, const int* __restrict__ seg,
                const float* __restrict__ outW, const float* __restrict__ outb,
                float* __restrict__ out)
{
    __shared__ float red[128];
    const int c = blockIdx.x;
    const int h = threadIdx.x;
    int l0, l1;
    {
        int l=0, r=N_ATOM;
        while (l<r){ int m=(l+r)>>1; if (seg[m] < c) l=m+1; else r=m; }
        l0 = l;
        l=l0; r=N_ATOM;
        while (l<r){ int m=(l+r)>>1; if (seg[m] < c+1) l=m+1; else r=m; }
        l1 = l;
    }
    float s = 0.f;
    for (int n = l0; n < l1; ++n) s += Z[(size_t)n*HID + h];
    float cnt = fmaxf((float)(l1-l0), 1.f);
    red[h] = (s/cnt) * outW[h];
    __syncthreads();
    for (int off=64; off>0; off>>=1){
        if (h < off) red[h] += red[h+off];
        __syncthreads();
    }
    if (h == 0) out[c] = red[0] + outb[0];
}

extern "C" void kernel_launch(void* const* d_in, const int* in_sizes, int n_in,
                              void* d_out, int out_size, void* d_ws, size_t ws_size,
                              hipStream_t stream)
{
    const float* atom_fea = (const float*)d_in[0];
    const float* nbr_fea  = (const float*)d_in[1];
    const int*   nbr_idx  = (const int*)d_in[2];
    const int*   site_seg = (const int*)d_in[3];
    const float* emb_W = (const float*)d_in[4];
    const float* emb_b = (const float*)d_in[5];
    const float* fcW   = (const float*)d_in[6];
    const float* fcb   = (const float*)d_in[7];
    const float* bn1_g = (const float*)d_in[8];
    const float* bn1_b = (const float*)d_in[9];
    const float* bn2_g = (const float*)d_in[10];
    const float* bn2_b = (const float*)d_in[11];
    const float* eW    = (const float*)d_in[12];
    const float* eb    = (const float*)d_in[13];
    const float* bne_g = (const float*)d_in[14];
    const float* bne_b = (const float*)d_in[15];
    const float* W3    = (const float*)d_in[16];
    const float* b3    = (const float*)d_in[17];
    const float* bn3_g = (const float*)d_in[18];
    const float* bn3_b = (const float*)d_in[19];
    const float* fc1W  = (const float*)d_in[20];
    const float* fc1b  = (const float*)d_in[21];
    const float* outW  = (const float*)d_in[22];
    const float* outb  = (const float*)d_in[23];

    // workspace layout (float units)
    float* ws   = (float*)d_ws;
    float* X    = ws;                          // 128,000
    float* E48  = ws + 128000;                 // 1,152,000 -> 1,280,000
    float* REST = ws + 1280000;                // 24000*512 = 12,288,000
    float* TB   = ws + 13568000;               // 128,000
    float* Z    = ws + 13696000;               // 256,000
    float* ST   = ws + 13952000;               // 3*2048 = 6,144
    //            ws + 13958144                // 1,024 spare (zeroed)
    float* SPQ  = ws + 13959168;               // 3 * 2 * 256,000 = 1,536,000
    __hip_bfloat16* WALL = (__hip_bfloat16*)(ws + 15495168); // 3*512*192 bf16
    float* BIAS = ws + 15642624;               // 1,536
    __hip_bfloat16* Xb   = (__hip_bfloat16*)(ws + 15644160); // 128,000 bf16 (64,000 f)
    __hip_bfloat16* E48b = (__hip_bfloat16*)(ws + 15708160); // 1,152,000 bf16 (576,000 f)
    // end: 16,284,160 floats

    {
        // flat prologue: 294,912 pack + 1,536 bias + 1,152,000 e_init + 1,543,168 zero
        const int total = 294912 + 1536 + 1152000 + 1543168;   // = 2,991,616
        prologue_k<<<total/256, 256, 0, stream>>>(fcW, eW, W3, fcb, eb, b3, nbr_fea,
                                                  WALL, BIAS, E48, E48b, ST);
    }
    emb_k<<<N_ATOM/16, 256, 0, stream>>>(atom_fea, emb_W, emb_b, X, Xb);

    for (int i = 0; i < NCONV; i++){
        float* STL = ST + i*2048;
        float* SPA = SPQ + (size_t)i*512000;
        float* SQA = SPA + 256000;

        {
            dim3 g((NM+127)/128, 4);
            gemm_fused<<<g, 256, 0, stream>>>((const unsigned short*)Xb,
                                              (const unsigned short*)E48b, nbr_idx,
                                              WALL + (size_t)i*512*LDA_T,
                                              BIAS + i*512, REST, STL, SPA, SQA);
        }
        bn3_pre<<<125, 256, 0, stream>>>(SPA, SQA, STL);
        consumer_k<<<N_ATOM, 256, 0, stream>>>(REST, STL, TB, E48, E48b,
                                               bn1_g + i*O1, bn1_b + i*O1,
                                               bne_g + i*OE, bne_b + i*OE,
                                               bn3_g + i*O1, bn3_b + i*O1);
        xupd_k<<<64, 256, 0, stream>>>(X, Xb, TB, STL,
                                       bn2_g + i*AF, bn2_b + i*AF);
    }

    // head: Z = softplus(softplus(X) @ fc1W^T + fc1b); pooled mean; out
    head_k<<<N_ATOM/16, 256, 0, stream>>>(X, fc1W, fc1b, Z);
    pool_out_k<<<NCRY, 128, 0, stream>>>(Z, site_seg, outW, outb, (float*)d_out);
}